// Round 13
// baseline (234.614 us; speedup 1.0000x reference)
//
#include <hip/hip_runtime.h>

typedef unsigned short u16t;
typedef unsigned int   u32t;
typedef __bf16 bf16x8 __attribute__((ext_vector_type(8)));
typedef float  f32x4  __attribute__((ext_vector_type(4)));

#define NB     4
#define SEQ    1024
#define DMODEL 1024
#define NHEAD  16
#define DEPTH  64
#define MAXSEQ 2048
#define MTOK   (NB * SEQ)   // 4096 token rows

#define AS1 __attribute__((address_space(1)))
#define AS3 __attribute__((address_space(3)))

// f32 -> bf16 RNE via hw v_cvt (compiler packs pairs into v_cvt_pk_bf16_f32).
__device__ __forceinline__ u16t f2bf(float f) {
  return __builtin_bit_cast(u16t, (__bf16)f);
}
__device__ __forceinline__ float bf2f(u16t h) {
  return __builtin_bit_cast(float, (u32t)h << 16);
}
__device__ __forceinline__ void load_lds16(const void* g, void* l) {
  __builtin_amdgcn_global_load_lds((AS1 u32t*)(g), (AS3 u32t*)(l), 16, 0, 0);
}
// partner-lane (t^1) value via DPP quad_perm [1,0,3,2] — VALU pipe, not LDS.
__device__ __forceinline__ float dpp_xor1(float x) {
  return __builtin_bit_cast(float, __builtin_amdgcn_update_dpp(
      0, __builtin_bit_cast(int, x), 0xB1, 0xF, 0xF, true));
}

// ---------------------------------------------------------------------------
// Prep kernels
// ---------------------------------------------------------------------------
__global__ void cvt3_kernel(const float* __restrict__ a, const float* __restrict__ b,
                            const float* __restrict__ c,
                            u16t* __restrict__ oa, u16t* __restrict__ ob,
                            u16t* __restrict__ oc, int n8) {
  int i = blockIdx.x * blockDim.x + threadIdx.x;
  if (i >= n8) return;
  const float* src = (blockIdx.z == 0) ? a : ((blockIdx.z == 1) ? b : c);
  u16t* dst = (blockIdx.z == 0) ? oa : ((blockIdx.z == 1) ? ob : oc);
  const float4* s4 = (const float4*)src;
  float4 x = s4[2 * i], y = s4[2 * i + 1];
  u16t tmp[8] = { f2bf(x.x), f2bf(x.y), f2bf(x.z), f2bf(x.w),
                  f2bf(y.x), f2bf(y.y), f2bf(y.z), f2bf(y.w) };
  ((uint4*)dst)[i] = *(const uint4*)tmp;
}

// z<4: WT[n][k] = bf16(W[k][n]).  z==4: Erel table Er[r][d]=bf16(pe[2047-r][d]).
__global__ void transpose4_kernel(const float* __restrict__ w0, const float* __restrict__ w1,
                                  const float* __restrict__ w2, const float* __restrict__ w3,
                                  u16t* __restrict__ t0, u16t* __restrict__ t1,
                                  u16t* __restrict__ t2, u16t* __restrict__ t3,
                                  const float* __restrict__ pe, u16t* __restrict__ Er) {
  const int z = blockIdx.z;
  if (z == 4) {
    const int flat = blockIdx.y * 32 + blockIdx.x;
    if (flat < 256) {
      const int idx = flat * 256 + threadIdx.x;     // SEQ*DEPTH = 65536
      const int r = idx >> 6, d = idx & 63;
      Er[idx] = f2bf(pe[(size_t)(MAXSEQ - 1 - r) * DEPTH + d]);
    }
    return;
  }
  const float* W = (z == 0) ? w0 : ((z == 1) ? w1 : ((z == 2) ? w2 : w3));
  u16t* WT = (z == 0) ? t0 : ((z == 1) ? t1 : ((z == 2) ? t2 : t3));
  __shared__ float tile[32][33];
  const int tx = threadIdx.x & 31, ty = threadIdx.x >> 5;   // 32x8
  const int bx = blockIdx.x * 32, by = blockIdx.y * 32;
#pragma unroll
  for (int r = 0; r < 32; r += 8)
    tile[ty + r][tx] = W[(size_t)(by + ty + r) * DMODEL + bx + tx];
  __syncthreads();
#pragma unroll
  for (int r = 0; r < 32; r += 8)
    WT[(size_t)(bx + ty + r) * DMODEL + by + tx] = f2bf(tile[tx][ty + r]);
}

// ---------------------------------------------------------------------------
// XCD-aware tile remap for (8 x 32) grids (verified: R7 gemm_qkv left top-5).
// ---------------------------------------------------------------------------
__device__ __forceinline__ void xcd_remap(int& bx, int& by) {
  const int flat = blockIdx.x + 8 * blockIdx.y;   // 0..255
  const int xv = flat & 7, pos = flat >> 3;       // xcd, 0..31
  bx = pos & 7;
  by = xv * 4 + (pos >> 3);
}

// ---------------------------------------------------------------------------
// GEMM: C[M x Nc] = (A[M x K](bf16) @ BT[Nc x K]^T(bf16) + bias) * scale
// ---------------------------------------------------------------------------
template <typename OutT>
__device__ __forceinline__ void gemm_bt_body(
    const u16t* __restrict__ A, const u16t* __restrict__ BT,
    const float* __restrict__ bias, OutT* __restrict__ C,
    int M, int Nc, int K, int bx, int by, float scale) {
  __shared__ __align__(16) u16t As[128 * 32];
  __shared__ __align__(16) u16t Bs[128 * 32];
  const int tid = threadIdx.x;
  const int wave = tid >> 6;
  const int lane = tid & 63;
  const int q = lane >> 4, t = lane & 15;
  const int lrow = lane >> 2, lch = lane & 3;
  const int bm = by * 128, bn = bx * 128;
  const int wi = (wave >> 1) * 64, wj = (wave & 1) * 64;

  f32x4 acc[4][4];
#pragma unroll
  for (int i = 0; i < 4; ++i)
#pragma unroll
    for (int j = 0; j < 4; ++j) acc[i][j] = f32x4{0.f, 0.f, 0.f, 0.f};

  for (int kt = 0; kt < K; kt += 32) {
    __syncthreads();
#pragma unroll
    for (int it = 0; it < 2; ++it) {
      const int rb = it * 64 + wave * 16;
      const u16t* ga = A + (size_t)(bm + rb + lrow) * K + kt + lch * 8;
      const u16t* gb = BT + (size_t)(bn + rb + lrow) * K + kt + lch * 8;
      load_lds16(ga, As + rb * 32);
      load_lds16(gb, Bs + rb * 32);
    }
    __syncthreads();
    bf16x8 af[4], bfr[4];
#pragma unroll
    for (int i = 0; i < 4; ++i) {
      af[i]  = *(const bf16x8*)(As + (wi + i * 16 + t) * 32 + q * 8);
      bfr[i] = *(const bf16x8*)(Bs + (wj + i * 16 + t) * 32 + q * 8);
    }
#pragma unroll
    for (int i = 0; i < 4; ++i)
#pragma unroll
      for (int j = 0; j < 4; ++j)
        acc[i][j] = __builtin_amdgcn_mfma_f32_16x16x32_bf16(af[i], bfr[j], acc[i][j], 0, 0, 0);
  }
#pragma unroll
  for (int j = 0; j < 4; ++j) {
    const int col = bn + wj + j * 16 + t;
    const float bv = bias[col];
#pragma unroll
    for (int i = 0; i < 4; ++i) {
#pragma unroll
      for (int r = 0; r < 4; ++r) {
        const int row = bm + wi + i * 16 + q * 4 + r;
        float v = (acc[i][j][r] + bv) * scale;
        if constexpr (sizeof(OutT) == 2) {
          C[(size_t)row * Nc + col] = f2bf(v);
        } else {
          C[(size_t)row * Nc + col] = v;
        }
      }
    }
  }
}

__global__ __launch_bounds__(256, 3) void gemm_qkv_kernel(
    const u16t* qa, const u16t* ka, const u16t* va,
    const u16t* wq, const u16t* wk, const u16t* wv,
    const float* bq, const float* bk, const float* bv,
    u16t* qo, u16t* ko, u16t* vo) {
  const int z = blockIdx.z;
  const u16t* A = (z == 0) ? qa : ((z == 1) ? ka : va);
  const u16t* B = (z == 0) ? wq : ((z == 1) ? wk : wv);
  const float* bb = (z == 0) ? bq : ((z == 1) ? bk : bv);
  u16t* C = (z == 0) ? qo : ((z == 1) ? ko : vo);
  const float scale = (z == 0) ? 0.125f : 1.0f;   // fold 1/sqrt(DEPTH) into Q
  int bx, by;
  xcd_remap(bx, by);
  gemm_bt_body<u16t>(A, B, bb, C, MTOK, DMODEL, DMODEL, bx, by, scale);
}

// ---------------------------------------------------------------------------
// Output GEMM: 256 blocks (1/CU), 512 threads (8 waves). XCD remap as above.
// ---------------------------------------------------------------------------
__global__ __launch_bounds__(512) void gemm_out_kernel(
    const u16t* __restrict__ A, const u16t* __restrict__ W,
    const float* __restrict__ bias, float* __restrict__ C) {
  __shared__ __align__(16) u16t As[128 * 32];
  __shared__ __align__(16) u16t Bs[128 * 32];
  const int tid = threadIdx.x;
  const int wave = tid >> 6, lane = tid & 63;
  const int q = lane >> 4, t = lane & 15;
  const int srow = wave * 16 + (lane >> 2);   // staging row 0..127
  const int sch = (lane & 3) * 8;             // staging k-offset
  int bx, by;
  xcd_remap(bx, by);
  const int bm = by * 128, bn = bx * 128;
  const int wi = (wave >> 1) * 32, wj = (wave & 1) * 64;
  const int K = DMODEL, Nc = DMODEL;

  f32x4 acc[2][4];
#pragma unroll
  for (int i = 0; i < 2; ++i)
#pragma unroll
    for (int j = 0; j < 4; ++j) acc[i][j] = f32x4{0.f, 0.f, 0.f, 0.f};

  for (int kt = 0; kt < K; kt += 32) {
    __syncthreads();
    load_lds16(A + (size_t)(bm + srow) * K + kt + sch, As + wave * 16 * 32);
    load_lds16(W + (size_t)(bn + srow) * K + kt + sch, Bs + wave * 16 * 32);
    __syncthreads();
    bf16x8 af[2], bfr[4];
#pragma unroll
    for (int i = 0; i < 2; ++i)
      af[i] = *(const bf16x8*)(As + (wi + i * 16 + t) * 32 + q * 8);
#pragma unroll
    for (int j = 0; j < 4; ++j)
      bfr[j] = *(const bf16x8*)(Bs + (wj + j * 16 + t) * 32 + q * 8);
#pragma unroll
    for (int i = 0; i < 2; ++i)
#pragma unroll
      for (int j = 0; j < 4; ++j)
        acc[i][j] = __builtin_amdgcn_mfma_f32_16x16x32_bf16(af[i], bfr[j], acc[i][j], 0, 0, 0);
  }
#pragma unroll
  for (int j = 0; j < 4; ++j) {
    const int col = bn + wj + j * 16 + t;
    const float bv = bias[col];
#pragma unroll
    for (int i = 0; i < 2; ++i) {
#pragma unroll
      for (int r = 0; r < 4; ++r) {
        const int row = bm + wi + i * 16 + q * 4 + r;
        C[(size_t)row * Nc + col] = acc[i][j][r] + bv;
      }
    }
  }
}

// ---------------------------------------------------------------------------
// Fused causal attention with relative-position bias — 128-row Q-tiles.
// R10 confirmed the binding resource is LDS instruction ISSUE (shuffle skew:
// 62.6->46.1 us at identical conflict count). R11's predicate-skips REVERTED
// (49.4 us: skips only helped non-critical-path waves; branches inside the
// unrolled Es/MFMA loop broke scheduling).
// THIS ROUND: P-store 16x ds_write_b16 -> 8x ds_write_b32. Lane pairs (t,t^1)
// exchange s[c][r] via DPP quad_perm [1,0,3,2] (VALU pipe, NOT ds_bpermute);
// even-t lanes emit the c in {0,1} column-pairs, odd-t lanes c in {2,3}, in
// the same 8 wave-uniform instructions (static reg indices + cndmask).
// Memory image byte-identical to the scalar path; P-read side unchanged.
// Structure: Es 256-slot delta-ring + Ks/Vt stride-72 + per-wave TP; bias
// skew via __shfl (R10); 2 barriers/iter; K/V/Es reg-prefetch; T5 setprio.
// Dispatch order: i-tiles {7,6,5,4} then {0,1,2,3}. Fixed-max softmax;
// Q pre-scaled by 0.125. LDS 73.7 KB -> 2 blocks/CU.
// ---------------------------------------------------------------------------
__global__ __launch_bounds__(512, 4) void attn_kernel(
    const u16t* __restrict__ Qp, const u16t* __restrict__ Kp,
    const u16t* __restrict__ Vp, const u16t* __restrict__ Er,
    u16t* __restrict__ AO) {
  const int gx = blockIdx.x;
  const int xcd = gx & 7, slot = gx >> 3;     // group pinned to XCD
  const int ghi = slot & 7, k4 = slot >> 3;   // k4 in [0,8)
  const int T = (k4 < 4) ? (7 - k4) : (k4 - 4);   // {7,6,5,4,0,1,2,3}
  const int g = (ghi << 3) | xcd;             // 0..63 = (n,h)
  const int n = g >> 4, h = g & 15;

  const int tid = threadIdx.x;
  const int wave = tid >> 6, lane = tid & 63;
  const int q = lane >> 4, t = lane & 15;
  const int rr = tid >> 3;          // 0..63 staging row
  const int c0 = (tid & 7) * 8;     // 0..56 staging d-offset

  __shared__ __align__(16) u16t Es[256 * 72];   // 36 KB delta-ring
  __shared__ __align__(16) u16t Ks[64 * 72];    // 9 KB
  __shared__ __align__(16) u16t Vt[64 * 72];    // 9 KB [d][j^swz], stride-72
  __shared__ __align__(16) u16t TP[8 * 1152];   // 18 KB per-wave P staging
  u16t* TPw = TP + wave * 1152;

  const int I0 = T * 128;
  const int iw = I0 + wave * 16;
  const int jmax = 2 * T + 1;

  const size_t qoff = ((size_t)(n * SEQ + iw + t)) * DMODEL + h * DEPTH;
  const bf16x8 qf0 = *(const bf16x8*)(Qp + qoff + q * 8);
  const bf16x8 qf1 = *(const bf16x8*)(Qp + qoff + 32 + q * 8);

  // ---- bias shuffle pattern: src lane + lo/hi select, per target row-reg r ----
  int srcl[4];
  bool sel_lo[4];
#pragma unroll
  for (int r = 0; r < 4; ++r) {
    const int u = q * 4 + r - 1 - t;
    srcl[r] = (q << 4) | (u & 15);
    sel_lo[r] = (u >= 0);
  }

  // ---- preload Es chunks 2T, 2T+1 (delta in [128T, 128T+128)) ----
  const uint4 epre0 = *(const uint4*)(Er + ((size_t)(2 * T) * 64 + rr) * DEPTH + c0);
  const uint4 epre1 = *(const uint4*)(Er + ((size_t)(2 * T + 1) * 64 + rr) * DEPTH + c0);
  // ---- iter-0 globals ----
  const size_t kvoff0 = ((size_t)(n * SEQ + rr)) * DMODEL + h * DEPTH + c0;   // J0=0
  uint4 kv = *(const uint4*)(Kp + kvoff0);
  uint4 vv = *(const uint4*)(Vp + kvoff0);
  // chunk 2T-1 (may be OOB-below for T=0: mapped guard, garbage masked)
  uint4 ev = *(const uint4*)(Er + ((ptrdiff_t)(2 * T - 1) * 64 + rr) * DEPTH + c0);

  *(uint4*)(Es + (((2 * T) & 3) * 64 + rr) * 72 + c0) = epre0;
  *(uint4*)(Es + (((2 * T + 1) & 3) * 64 + rr) * 72 + c0) = epre1;

  f32x4 o[4];
#pragma unroll
  for (int c = 0; c < 4; ++c) o[c] = f32x4{0.f, 0.f, 0.f, 0.f};
  float l_r[4] = {0.f, 0.f, 0.f, 0.f};

  for (int jt = 0; jt <= jmax; ++jt) {
    const int J0 = jt * 64;
    const int cnew = 2 * T - 1 - jt;          // chunk staged this iter

    __syncthreads();    // previous tile fully consumed
    // ---- stage K (stride-72), Es chunk (ring, stride-72), V (transposed) ----
    *(uint4*)(Ks + rr * 72 + c0) = kv;
    *(uint4*)(Es + ((cnew & 3) * 64 + rr) * 72 + c0) = ev;
    {
      const u16t* pv = (const u16t*)&vv;
#pragma unroll
      for (int uu = 0; uu < 8; ++uu) {
        const int d = c0 + uu;
        Vt[d * 72 + (rr ^ (((d >> 2) & 7) << 3))] = pv[uu];
      }
    }
    __syncthreads();

    // ---- prefetch next-iter globals (drain overlaps compute) ----
    if (jt < jmax) {
      const size_t kvoff = ((size_t)(n * SEQ + J0 + 64 + rr)) * DMODEL + h * DEPTH + c0;
      kv = *(const uint4*)(Kp + kvoff);
      vv = *(const uint4*)(Vp + kvoff);
      ev = *(const uint4*)(Er + ((ptrdiff_t)(cnew - 1) * 64 + rr) * DEPTH + c0);
    }

    // ---- QK^T (K frags from stride-72 LDS) ----
    __builtin_amdgcn_s_setprio(1);
    f32x4 s[4];
#pragma unroll
    for (int c = 0; c < 4; ++c) s[c] = f32x4{0.f, 0.f, 0.f, 0.f};
#pragma unroll
    for (int kk = 0; kk < 2; ++kk) {
      const bf16x8 qf = kk ? qf1 : qf0;
#pragma unroll
      for (int c = 0; c < 4; ++c) {
        const bf16x8 kf = *(const bf16x8*)(Ks + (c * 16 + t) * 72 + kk * 32 + q * 8);
        s[c] = __builtin_amdgcn_mfma_f32_16x16x32_bf16(qf, kf, s[c], 0, 0, 0);
      }
    }
    // ---- bias T = Q @ Es^T over this wave's 80-wide delta window ----
    const int D0 = iw - J0 - 63;   // delta of window col 0
    f32x4 tb[5];
#pragma unroll
    for (int cc = 0; cc < 5; ++cc) tb[cc] = f32x4{0.f, 0.f, 0.f, 0.f};
#pragma unroll
    for (int kk = 0; kk < 2; ++kk) {
      const bf16x8 qf = kk ? qf1 : qf0;
#pragma unroll
      for (int cc = 0; cc < 5; ++cc) {
        const int sl = (int)(((unsigned)(D0 + cc * 16 + t)) & 255u);
        const bf16x8 ef = *(const bf16x8*)(Es + sl * 72 + kk * 32 + q * 8);
        tb[cc] = __builtin_amdgcn_mfma_f32_16x16x32_bf16(qf, ef, tb[cc], 0, 0, 0);
      }
    }
    __builtin_amdgcn_s_setprio(0);

    // ---- skew transfer in-register: sh[cc][r] = tb[cc][r] from srcl[r] ----
    float sh[5][4];
#pragma unroll
    for (int cc = 0; cc < 5; ++cc)
#pragma unroll
      for (int r = 0; r < 4; ++r)
        sh[cc][r] = __shfl(tb[cc][r], srcl[r], 64);

    // ---- logits + causal mask + fixed-max softmax numerator ----
    const int dIJ = I0 - J0;
#pragma unroll
    for (int c = 0; c < 4; ++c) {
      const int jc = c * 16 + t;               // j - J0
#pragma unroll
      for (int r = 0; r < 4; ++r) {
        const int ic = wave * 16 + q * 4 + r;  // i - I0
        const float bias = sel_lo[r] ? sh[4 - c][r] : sh[3 - c][r];
        float lg = s[c][r] + bias;
        lg = (jc <= ic + dIJ) ? lg : -1e30f;
        const float pr = __expf(lg);
        s[c][r] = pr;
        l_r[r] += pr;
      }
    }

    // ---- P -> LDS, paired b32 writes (8 wave-instrs instead of 16).
    //      Lane pairs (t, t^1) exchange via DPP quad_perm; even t emits
    //      c in {0,1} pairs, odd t c in {2,3}. Same memory image. ----
    {
      const int isOdd = t & 1;
      const int tEven = t & ~1;
      u32t* TPw32 = (u32t*)TPw;
#pragma unroll
      for (int ch = 0; ch < 2; ++ch) {
#pragma unroll
        for (int r = 0; r < 4; ++r) {
          const float lo_own = s[ch][r];        // c = ch
          const float hi_own = s[2 + ch][r];    // c = 2+ch
          const float lo_dpp = dpp_xor1(lo_own);
          const float hi_dpp = dpp_xor1(hi_own);
          const float vlo = isOdd ? hi_dpp : lo_own;   // col tEven
          const float vhi = isOdd ? hi_own : lo_dpp;   // col tEven+1
          const u32t pk = (u32t)f2bf(vlo) | ((u32t)f2bf(vhi) << 16);
          const int cw = isOdd ? (2 + ch) : ch;
          TPw32[((q * 4 + r) * 72 + cw * 16 + tEven) >> 1] = pk;
        }
      }
    }

    const bf16x8 pf0 = *(const bf16x8*)(TPw + t * 72 + q * 8);
    const bf16x8 pf1 = *(const bf16x8*)(TPw + t * 72 + 32 + q * 8);
    __builtin_amdgcn_s_setprio(1);
#pragma unroll
    for (int c2 = 0; c2 < 4; ++c2) {
      const int dd = c2 * 16 + t;
      const int sw = (dd >> 2) & 7;
      const bf16x8 v0 = *(const bf16x8*)(Vt + dd * 72 + ((0 + q) ^ sw) * 8);
      const bf16x8 v1 = *(const bf16x8*)(Vt + dd * 72 + ((4 + q) ^ sw) * 8);
      o[c2] = __builtin_amdgcn_mfma_f32_16x16x32_bf16(pf0, v0, o[c2], 0, 0, 0);
      o[c2] = __builtin_amdgcn_mfma_f32_16x16x32_bf16(pf1, v1, o[c2], 0, 0, 0);
    }
    __builtin_amdgcn_s_setprio(0);
  }

  // ---- epilogue: reduce l over the 16 t-lanes, normalize, store ----
#pragma unroll
  for (int r = 0; r < 4; ++r) {
    float lsum = l_r[r];
    lsum += __shfl_xor(lsum, 1, 64);
    lsum += __shfl_xor(lsum, 2, 64);
    lsum += __shfl_xor(lsum, 4, 64);
    lsum += __shfl_xor(lsum, 8, 64);
    const float inv = 1.f / lsum;
    const size_t obase = ((size_t)(n * SEQ + iw + q * 4 + r)) * DMODEL + h * DEPTH;
#pragma unroll
    for (int c2 = 0; c2 < 4; ++c2)
      AO[obase + c2 * 16 + t] = f2bf(o[c2][r] * inv);
  }
}

// ---------------------------------------------------------------------------
extern "C" void kernel_launch(void* const* d_in, const int* in_sizes, int n_in,
                              void* d_out, int out_size, void* d_ws, size_t ws_size,
                              hipStream_t stream) {
  const float* q_in = (const float*)d_in[0];
  const float* k_in = (const float*)d_in[1];
  const float* v_in = (const float*)d_in[2];
  // d_in[3] = mask (causal; analytic)
  const float* Wq = (const float*)d_in[4];
  const float* bq = (const float*)d_in[5];
  const float* Wk = (const float*)d_in[6];
  const float* bk = (const float*)d_in[7];
  const float* Wv = (const float*)d_in[8];
  const float* bv = (const float*)d_in[9];
  const float* Wo = (const float*)d_in[10];
  const float* bo = (const float*)d_in[11];
  const float* pe = (const float*)d_in[12];
  float* out = (float*)d_out;

  char* ws = (char*)d_ws;
  constexpr size_t MB = 1ull << 20;
  u16t* qb  = (u16t*)(ws);            // 8 MB [prep..qkv]
  u16t* kb  = (u16t*)(ws + 8 * MB);
  u16t* vb  = (u16t*)(ws + 16 * MB);
  u16t* Qp  = (u16t*)(ws + 24 * MB);
  u16t* Kp  = (u16t*)(ws + 32 * MB);
  u16t* Vp  = (u16t*)(ws + 40 * MB);
  u16t* AOb = (u16t*)(ws + 48 * MB);
  u16t* WqT = (u16t*)(ws + 56 * MB);
  u16t* WkT = (u16t*)(ws + 58 * MB);
  u16t* WvT = (u16t*)(ws + 60 * MB);
  u16t* WoT = (u16t*)(ws + 62 * MB);
  // Erel at +64MB+16KB: 16 KB mapped guard below (ring chunk reads reach
  // down to Erl-16KB for fully-masked windows), 128 KB table above.
  u16t* Erl = (u16t*)(ws + 64 * MB + 16 * 1024);

  const size_t SZA = (size_t)MTOK * DMODEL;
  const int n8 = (int)(SZA / 8);
  cvt3_kernel<<<dim3(n8 / 256, 1, 3), 256, 0, stream>>>(q_in, k_in, v_in, qb, kb, vb, n8);
  transpose4_kernel<<<dim3(32, 32, 5), 256, 0, stream>>>(Wq, Wk, Wv, Wo, WqT, WkT, WvT, WoT,
                                                         pe, Erl);

  gemm_qkv_kernel<<<dim3(DMODEL / 128, MTOK / 128, 3), 256, 0, stream>>>(
      qb, kb, vb, WqT, WkT, WvT, bq, bk, bv, Qp, Kp, Vp);

  attn_kernel<<<dim3(512, 1, 1), 512, 0, stream>>>(Qp, Kp, Vp, Erl, AOb);

  gemm_out_kernel<<<dim3(DMODEL / 128, MTOK / 128, 1), 512, 0, stream>>>(AOb, WoT, bo, out);
}

// Round 14
// 223.999 us; speedup vs baseline: 1.0474x; 1.0474x over previous
//
#include <hip/hip_runtime.h>

typedef unsigned short u16t;
typedef unsigned int   u32t;
typedef __bf16 bf16x8 __attribute__((ext_vector_type(8)));
typedef float  f32x4  __attribute__((ext_vector_type(4)));

#define NB     4
#define SEQ    1024
#define DMODEL 1024
#define NHEAD  16
#define DEPTH  64
#define MAXSEQ 2048
#define MTOK   (NB * SEQ)   // 4096 token rows

#define AS1 __attribute__((address_space(1)))
#define AS3 __attribute__((address_space(3)))

// f32 -> bf16 RNE via hw v_cvt (compiler packs pairs into v_cvt_pk_bf16_f32).
__device__ __forceinline__ u16t f2bf(float f) {
  return __builtin_bit_cast(u16t, (__bf16)f);
}
__device__ __forceinline__ float bf2f(u16t h) {
  return __builtin_bit_cast(float, (u32t)h << 16);
}
__device__ __forceinline__ void load_lds16(const void* g, void* l) {
  __builtin_amdgcn_global_load_lds((AS1 u32t*)(g), (AS3 u32t*)(l), 16, 0, 0);
}

// ---------------------------------------------------------------------------
// Prep kernels
// ---------------------------------------------------------------------------
__global__ void cvt3_kernel(const float* __restrict__ a, const float* __restrict__ b,
                            const float* __restrict__ c,
                            u16t* __restrict__ oa, u16t* __restrict__ ob,
                            u16t* __restrict__ oc, int n8) {
  int i = blockIdx.x * blockDim.x + threadIdx.x;
  if (i >= n8) return;
  const float* src = (blockIdx.z == 0) ? a : ((blockIdx.z == 1) ? b : c);
  u16t* dst = (blockIdx.z == 0) ? oa : ((blockIdx.z == 1) ? ob : oc);
  const float4* s4 = (const float4*)src;
  float4 x = s4[2 * i], y = s4[2 * i + 1];
  u16t tmp[8] = { f2bf(x.x), f2bf(x.y), f2bf(x.z), f2bf(x.w),
                  f2bf(y.x), f2bf(y.y), f2bf(y.z), f2bf(y.w) };
  ((uint4*)dst)[i] = *(const uint4*)tmp;
}

// z<4: WT[n][k] = bf16(W[k][n]).  z==4: Erel table Er[r][d]=bf16(pe[2047-r][d]).
__global__ void transpose4_kernel(const float* __restrict__ w0, const float* __restrict__ w1,
                                  const float* __restrict__ w2, const float* __restrict__ w3,
                                  u16t* __restrict__ t0, u16t* __restrict__ t1,
                                  u16t* __restrict__ t2, u16t* __restrict__ t3,
                                  const float* __restrict__ pe, u16t* __restrict__ Er) {
  const int z = blockIdx.z;
  if (z == 4) {
    const int flat = blockIdx.y * 32 + blockIdx.x;
    if (flat < 256) {
      const int idx = flat * 256 + threadIdx.x;     // SEQ*DEPTH = 65536
      const int r = idx >> 6, d = idx & 63;
      Er[idx] = f2bf(pe[(size_t)(MAXSEQ - 1 - r) * DEPTH + d]);
    }
    return;
  }
  const float* W = (z == 0) ? w0 : ((z == 1) ? w1 : ((z == 2) ? w2 : w3));
  u16t* WT = (z == 0) ? t0 : ((z == 1) ? t1 : ((z == 2) ? t2 : t3));
  __shared__ float tile[32][33];
  const int tx = threadIdx.x & 31, ty = threadIdx.x >> 5;   // 32x8
  const int bx = blockIdx.x * 32, by = blockIdx.y * 32;
#pragma unroll
  for (int r = 0; r < 32; r += 8)
    tile[ty + r][tx] = W[(size_t)(by + ty + r) * DMODEL + bx + tx];
  __syncthreads();
#pragma unroll
  for (int r = 0; r < 32; r += 8)
    WT[(size_t)(bx + ty + r) * DMODEL + by + tx] = f2bf(tile[tx][ty + r]);
}

// ---------------------------------------------------------------------------
// XCD-aware tile remap for (8 x 32) grids (verified: R7 gemm_qkv left top-5).
// ---------------------------------------------------------------------------
__device__ __forceinline__ void xcd_remap(int& bx, int& by) {
  const int flat = blockIdx.x + 8 * blockIdx.y;   // 0..255
  const int xv = flat & 7, pos = flat >> 3;       // xcd, 0..31
  bx = pos & 7;
  by = xv * 4 + (pos >> 3);
}

// ---------------------------------------------------------------------------
// GEMM: C[M x Nc] = (A[M x K](bf16) @ BT[Nc x K]^T(bf16) + bias) * scale
// ---------------------------------------------------------------------------
template <typename OutT>
__device__ __forceinline__ void gemm_bt_body(
    const u16t* __restrict__ A, const u16t* __restrict__ BT,
    const float* __restrict__ bias, OutT* __restrict__ C,
    int M, int Nc, int K, int bx, int by, float scale) {
  __shared__ __align__(16) u16t As[128 * 32];
  __shared__ __align__(16) u16t Bs[128 * 32];
  const int tid = threadIdx.x;
  const int wave = tid >> 6;
  const int lane = tid & 63;
  const int q = lane >> 4, t = lane & 15;
  const int lrow = lane >> 2, lch = lane & 3;
  const int bm = by * 128, bn = bx * 128;
  const int wi = (wave >> 1) * 64, wj = (wave & 1) * 64;

  f32x4 acc[4][4];
#pragma unroll
  for (int i = 0; i < 4; ++i)
#pragma unroll
    for (int j = 0; j < 4; ++j) acc[i][j] = f32x4{0.f, 0.f, 0.f, 0.f};

  for (int kt = 0; kt < K; kt += 32) {
    __syncthreads();
#pragma unroll
    for (int it = 0; it < 2; ++it) {
      const int rb = it * 64 + wave * 16;
      const u16t* ga = A + (size_t)(bm + rb + lrow) * K + kt + lch * 8;
      const u16t* gb = BT + (size_t)(bn + rb + lrow) * K + kt + lch * 8;
      load_lds16(ga, As + rb * 32);
      load_lds16(gb, Bs + rb * 32);
    }
    __syncthreads();
    bf16x8 af[4], bfr[4];
#pragma unroll
    for (int i = 0; i < 4; ++i) {
      af[i]  = *(const bf16x8*)(As + (wi + i * 16 + t) * 32 + q * 8);
      bfr[i] = *(const bf16x8*)(Bs + (wj + i * 16 + t) * 32 + q * 8);
    }
#pragma unroll
    for (int i = 0; i < 4; ++i)
#pragma unroll
      for (int j = 0; j < 4; ++j)
        acc[i][j] = __builtin_amdgcn_mfma_f32_16x16x32_bf16(af[i], bfr[j], acc[i][j], 0, 0, 0);
  }
#pragma unroll
  for (int j = 0; j < 4; ++j) {
    const int col = bn + wj + j * 16 + t;
    const float bv = bias[col];
#pragma unroll
    for (int i = 0; i < 4; ++i) {
#pragma unroll
      for (int r = 0; r < 4; ++r) {
        const int row = bm + wi + i * 16 + q * 4 + r;
        float v = (acc[i][j][r] + bv) * scale;
        if constexpr (sizeof(OutT) == 2) {
          C[(size_t)row * Nc + col] = f2bf(v);
        } else {
          C[(size_t)row * Nc + col] = v;
        }
      }
    }
  }
}

__global__ __launch_bounds__(256, 3) void gemm_qkv_kernel(
    const u16t* qa, const u16t* ka, const u16t* va,
    const u16t* wq, const u16t* wk, const u16t* wv,
    const float* bq, const float* bk, const float* bv,
    u16t* qo, u16t* ko, u16t* vo) {
  const int z = blockIdx.z;
  const u16t* A = (z == 0) ? qa : ((z == 1) ? ka : va);
  const u16t* B = (z == 0) ? wq : ((z == 1) ? wk : wv);
  const float* bb = (z == 0) ? bq : ((z == 1) ? bk : bv);
  u16t* C = (z == 0) ? qo : ((z == 1) ? ko : vo);
  const float scale = (z == 0) ? 0.125f : 1.0f;   // fold 1/sqrt(DEPTH) into Q
  int bx, by;
  xcd_remap(bx, by);
  gemm_bt_body<u16t>(A, B, bb, C, MTOK, DMODEL, DMODEL, bx, by, scale);
}

// ---------------------------------------------------------------------------
// Output GEMM: 256 blocks (1/CU), 512 threads (8 waves). XCD remap as above.
// ---------------------------------------------------------------------------
__global__ __launch_bounds__(512) void gemm_out_kernel(
    const u16t* __restrict__ A, const u16t* __restrict__ W,
    const float* __restrict__ bias, float* __restrict__ C) {
  __shared__ __align__(16) u16t As[128 * 32];
  __shared__ __align__(16) u16t Bs[128 * 32];
  const int tid = threadIdx.x;
  const int wave = tid >> 6, lane = tid & 63;
  const int q = lane >> 4, t = lane & 15;
  const int srow = wave * 16 + (lane >> 2);   // staging row 0..127
  const int sch = (lane & 3) * 8;             // staging k-offset
  int bx, by;
  xcd_remap(bx, by);
  const int bm = by * 128, bn = bx * 128;
  const int wi = (wave >> 1) * 32, wj = (wave & 1) * 64;
  const int K = DMODEL, Nc = DMODEL;

  f32x4 acc[2][4];
#pragma unroll
  for (int i = 0; i < 2; ++i)
#pragma unroll
    for (int j = 0; j < 4; ++j) acc[i][j] = f32x4{0.f, 0.f, 0.f, 0.f};

  for (int kt = 0; kt < K; kt += 32) {
    __syncthreads();
    load_lds16(A + (size_t)(bm + srow) * K + kt + sch, As + wave * 16 * 32);
    load_lds16(W + (size_t)(bn + srow) * K + kt + sch, Bs + wave * 16 * 32);
    __syncthreads();
    bf16x8 af[2], bfr[4];
#pragma unroll
    for (int i = 0; i < 2; ++i)
      af[i] = *(const bf16x8*)(As + (wi + i * 16 + t) * 32 + q * 8);
#pragma unroll
    for (int j = 0; j < 4; ++j)
      bfr[j] = *(const bf16x8*)(Bs + (wj + j * 16 + t) * 32 + q * 8);
#pragma unroll
    for (int i = 0; i < 2; ++i)
#pragma unroll
      for (int j = 0; j < 4; ++j)
        acc[i][j] = __builtin_amdgcn_mfma_f32_16x16x32_bf16(af[i], bfr[j], acc[i][j], 0, 0, 0);
  }
#pragma unroll
  for (int j = 0; j < 4; ++j) {
    const int col = bn + wj + j * 16 + t;
    const float bv = bias[col];
#pragma unroll
    for (int i = 0; i < 2; ++i) {
#pragma unroll
      for (int r = 0; r < 4; ++r) {
        const int row = bm + wi + i * 16 + q * 4 + r;
        C[(size_t)row * Nc + col] = acc[i][j][r] + bv;
      }
    }
  }
}

// ---------------------------------------------------------------------------
// Fused causal attention with relative-position bias — 128-row Q-tiles.
// == R10 kernel (session best: 223.7 us total, attn warm 46.1 us) ==
// R10 confirmed the binding resource is LDS instruction ISSUE (shuffle-based
// skew transfer: 62.6->46.1 us at identical conflict count).
// REVERTED experiments (kept for the record):
//  * R11 predicate-skips (49.4): skips only helped non-critical-path waves;
//    branches inside the unrolled Es/MFMA loop broke scheduling.
//  * R13 DPP-paired P-store (55.3): cross-lane pair dependency serialized
//    the P-store behind BOTH lanes' exp chains; bank conflicts rose 4.7->5.3M.
//  Lesson: remove LDS ops only when it adds NO new dependency/control flow.
// Structure: Es 256-slot delta-ring + Ks/Vt stride-72 + per-wave TP; bias
// skew via __shfl (R10); 2 barriers/iter; K/V/Es reg-prefetch; T5 setprio.
// Dispatch order: i-tiles {7,6,5,4} then {0,1,2,3}. Fixed-max softmax;
// Q pre-scaled by 0.125. LDS 73.7 KB -> 2 blocks/CU.
// ---------------------------------------------------------------------------
__global__ __launch_bounds__(512, 4) void attn_kernel(
    const u16t* __restrict__ Qp, const u16t* __restrict__ Kp,
    const u16t* __restrict__ Vp, const u16t* __restrict__ Er,
    u16t* __restrict__ AO) {
  const int gx = blockIdx.x;
  const int xcd = gx & 7, slot = gx >> 3;     // group pinned to XCD
  const int ghi = slot & 7, k4 = slot >> 3;   // k4 in [0,8)
  const int T = (k4 < 4) ? (7 - k4) : (k4 - 4);   // {7,6,5,4,0,1,2,3}
  const int g = (ghi << 3) | xcd;             // 0..63 = (n,h)
  const int n = g >> 4, h = g & 15;

  const int tid = threadIdx.x;
  const int wave = tid >> 6, lane = tid & 63;
  const int q = lane >> 4, t = lane & 15;
  const int rr = tid >> 3;          // 0..63 staging row
  const int c0 = (tid & 7) * 8;     // 0..56 staging d-offset

  __shared__ __align__(16) u16t Es[256 * 72];   // 36 KB delta-ring
  __shared__ __align__(16) u16t Ks[64 * 72];    // 9 KB
  __shared__ __align__(16) u16t Vt[64 * 72];    // 9 KB [d][j^swz], stride-72
  __shared__ __align__(16) u16t TP[8 * 1152];   // 18 KB per-wave P staging
  u16t* TPw = TP + wave * 1152;

  const int I0 = T * 128;
  const int iw = I0 + wave * 16;
  const int jmax = 2 * T + 1;

  const size_t qoff = ((size_t)(n * SEQ + iw + t)) * DMODEL + h * DEPTH;
  const bf16x8 qf0 = *(const bf16x8*)(Qp + qoff + q * 8);
  const bf16x8 qf1 = *(const bf16x8*)(Qp + qoff + 32 + q * 8);

  // ---- bias shuffle pattern: src lane + lo/hi select, per target row-reg r ----
  int srcl[4];
  bool sel_lo[4];
#pragma unroll
  for (int r = 0; r < 4; ++r) {
    const int u = q * 4 + r - 1 - t;
    srcl[r] = (q << 4) | (u & 15);
    sel_lo[r] = (u >= 0);
  }

  // ---- preload Es chunks 2T, 2T+1 (delta in [128T, 128T+128)) ----
  const uint4 epre0 = *(const uint4*)(Er + ((size_t)(2 * T) * 64 + rr) * DEPTH + c0);
  const uint4 epre1 = *(const uint4*)(Er + ((size_t)(2 * T + 1) * 64 + rr) * DEPTH + c0);
  // ---- iter-0 globals ----
  const size_t kvoff0 = ((size_t)(n * SEQ + rr)) * DMODEL + h * DEPTH + c0;   // J0=0
  uint4 kv = *(const uint4*)(Kp + kvoff0);
  uint4 vv = *(const uint4*)(Vp + kvoff0);
  // chunk 2T-1 (may be OOB-below for T=0: mapped guard, garbage masked)
  uint4 ev = *(const uint4*)(Er + ((ptrdiff_t)(2 * T - 1) * 64 + rr) * DEPTH + c0);

  *(uint4*)(Es + (((2 * T) & 3) * 64 + rr) * 72 + c0) = epre0;
  *(uint4*)(Es + (((2 * T + 1) & 3) * 64 + rr) * 72 + c0) = epre1;

  f32x4 o[4];
#pragma unroll
  for (int c = 0; c < 4; ++c) o[c] = f32x4{0.f, 0.f, 0.f, 0.f};
  float l_r[4] = {0.f, 0.f, 0.f, 0.f};

  for (int jt = 0; jt <= jmax; ++jt) {
    const int J0 = jt * 64;
    const int cnew = 2 * T - 1 - jt;          // chunk staged this iter

    __syncthreads();    // previous tile fully consumed
    // ---- stage K (stride-72), Es chunk (ring, stride-72), V (transposed) ----
    *(uint4*)(Ks + rr * 72 + c0) = kv;
    *(uint4*)(Es + ((cnew & 3) * 64 + rr) * 72 + c0) = ev;
    {
      const u16t* pv = (const u16t*)&vv;
#pragma unroll
      for (int uu = 0; uu < 8; ++uu) {
        const int d = c0 + uu;
        Vt[d * 72 + (rr ^ (((d >> 2) & 7) << 3))] = pv[uu];
      }
    }
    __syncthreads();

    // ---- prefetch next-iter globals (drain overlaps compute) ----
    if (jt < jmax) {
      const size_t kvoff = ((size_t)(n * SEQ + J0 + 64 + rr)) * DMODEL + h * DEPTH + c0;
      kv = *(const uint4*)(Kp + kvoff);
      vv = *(const uint4*)(Vp + kvoff);
      ev = *(const uint4*)(Er + ((ptrdiff_t)(cnew - 1) * 64 + rr) * DEPTH + c0);
    }

    // ---- QK^T (K frags from stride-72 LDS) ----
    __builtin_amdgcn_s_setprio(1);
    f32x4 s[4];
#pragma unroll
    for (int c = 0; c < 4; ++c) s[c] = f32x4{0.f, 0.f, 0.f, 0.f};
#pragma unroll
    for (int kk = 0; kk < 2; ++kk) {
      const bf16x8 qf = kk ? qf1 : qf0;
#pragma unroll
      for (int c = 0; c < 4; ++c) {
        const bf16x8 kf = *(const bf16x8*)(Ks + (c * 16 + t) * 72 + kk * 32 + q * 8);
        s[c] = __builtin_amdgcn_mfma_f32_16x16x32_bf16(qf, kf, s[c], 0, 0, 0);
      }
    }
    // ---- bias T = Q @ Es^T over this wave's 80-wide delta window ----
    const int D0 = iw - J0 - 63;   // delta of window col 0
    f32x4 tb[5];
#pragma unroll
    for (int cc = 0; cc < 5; ++cc) tb[cc] = f32x4{0.f, 0.f, 0.f, 0.f};
#pragma unroll
    for (int kk = 0; kk < 2; ++kk) {
      const bf16x8 qf = kk ? qf1 : qf0;
#pragma unroll
      for (int cc = 0; cc < 5; ++cc) {
        const int sl = (int)(((unsigned)(D0 + cc * 16 + t)) & 255u);
        const bf16x8 ef = *(const bf16x8*)(Es + sl * 72 + kk * 32 + q * 8);
        tb[cc] = __builtin_amdgcn_mfma_f32_16x16x32_bf16(qf, ef, tb[cc], 0, 0, 0);
      }
    }
    __builtin_amdgcn_s_setprio(0);

    // ---- skew transfer in-register: sh[cc][r] = tb[cc][r] from srcl[r] ----
    float sh[5][4];
#pragma unroll
    for (int cc = 0; cc < 5; ++cc)
#pragma unroll
      for (int r = 0; r < 4; ++r)
        sh[cc][r] = __shfl(tb[cc][r], srcl[r], 64);

    // ---- logits + causal mask + fixed-max softmax numerator ----
    const int dIJ = I0 - J0;
#pragma unroll
    for (int c = 0; c < 4; ++c) {
      const int jc = c * 16 + t;               // j - J0
#pragma unroll
      for (int r = 0; r < 4; ++r) {
        const int ic = wave * 16 + q * 4 + r;  // i - I0
        const float bias = sel_lo[r] ? sh[4 - c][r] : sh[3 - c][r];
        float lg = s[c][r] + bias;
        lg = (jc <= ic + dIJ) ? lg : -1e30f;
        const float pr = __expf(lg);
        s[c][r] = pr;
        l_r[r] += pr;
      }
    }
    // ---- P -> LDS in A-operand layout (same-wave order) ----
#pragma unroll
    for (int c = 0; c < 4; ++c)
#pragma unroll
      for (int r = 0; r < 4; ++r)
        TPw[(q * 4 + r) * 72 + c * 16 + t] = f2bf(s[c][r]);

    const bf16x8 pf0 = *(const bf16x8*)(TPw + t * 72 + q * 8);
    const bf16x8 pf1 = *(const bf16x8*)(TPw + t * 72 + 32 + q * 8);
    __builtin_amdgcn_s_setprio(1);
#pragma unroll
    for (int c2 = 0; c2 < 4; ++c2) {
      const int dd = c2 * 16 + t;
      const int sw = (dd >> 2) & 7;
      const bf16x8 v0 = *(const bf16x8*)(Vt + dd * 72 + ((0 + q) ^ sw) * 8);
      const bf16x8 v1 = *(const bf16x8*)(Vt + dd * 72 + ((4 + q) ^ sw) * 8);
      o[c2] = __builtin_amdgcn_mfma_f32_16x16x32_bf16(pf0, v0, o[c2], 0, 0, 0);
      o[c2] = __builtin_amdgcn_mfma_f32_16x16x32_bf16(pf1, v1, o[c2], 0, 0, 0);
    }
    __builtin_amdgcn_s_setprio(0);
  }

  // ---- epilogue: reduce l over the 16 t-lanes, normalize, store ----
#pragma unroll
  for (int r = 0; r < 4; ++r) {
    float lsum = l_r[r];
    lsum += __shfl_xor(lsum, 1, 64);
    lsum += __shfl_xor(lsum, 2, 64);
    lsum += __shfl_xor(lsum, 4, 64);
    lsum += __shfl_xor(lsum, 8, 64);
    const float inv = 1.f / lsum;
    const size_t obase = ((size_t)(n * SEQ + iw + q * 4 + r)) * DMODEL + h * DEPTH;
#pragma unroll
    for (int c2 = 0; c2 < 4; ++c2)
      AO[obase + c2 * 16 + t] = f2bf(o[c2][r] * inv);
  }
}

// ---------------------------------------------------------------------------
extern "C" void kernel_launch(void* const* d_in, const int* in_sizes, int n_in,
                              void* d_out, int out_size, void* d_ws, size_t ws_size,
                              hipStream_t stream) {
  const float* q_in = (const float*)d_in[0];
  const float* k_in = (const float*)d_in[1];
  const float* v_in = (const float*)d_in[2];
  // d_in[3] = mask (causal; analytic)
  const float* Wq = (const float*)d_in[4];
  const float* bq = (const float*)d_in[5];
  const float* Wk = (const float*)d_in[6];
  const float* bk = (const float*)d_in[7];
  const float* Wv = (const float*)d_in[8];
  const float* bv = (const float*)d_in[9];
  const float* Wo = (const float*)d_in[10];
  const float* bo = (const float*)d_in[11];
  const float* pe = (const float*)d_in[12];
  float* out = (float*)d_out;

  char* ws = (char*)d_ws;
  constexpr size_t MB = 1ull << 20;
  u16t* qb  = (u16t*)(ws);            // 8 MB [prep..qkv]
  u16t* kb  = (u16t*)(ws + 8 * MB);
  u16t* vb  = (u16t*)(ws + 16 * MB);
  u16t* Qp  = (u16t*)(ws + 24 * MB);
  u16t* Kp  = (u16t*)(ws + 32 * MB);
  u16t* Vp  = (u16t*)(ws + 40 * MB);
  u16t* AOb = (u16t*)(ws + 48 * MB);
  u16t* WqT = (u16t*)(ws + 56 * MB);
  u16t* WkT = (u16t*)(ws + 58 * MB);
  u16t* WvT = (u16t*)(ws + 60 * MB);
  u16t* WoT = (u16t*)(ws + 62 * MB);
  // Erel at +64MB+16KB: 16 KB mapped guard below (ring chunk reads reach
  // down to Erl-16KB for fully-masked windows), 128 KB table above.
  u16t* Erl = (u16t*)(ws + 64 * MB + 16 * 1024);

  const size_t SZA = (size_t)MTOK * DMODEL;
  const int n8 = (int)(SZA / 8);
  cvt3_kernel<<<dim3(n8 / 256, 1, 3), 256, 0, stream>>>(q_in, k_in, v_in, qb, kb, vb, n8);
  transpose4_kernel<<<dim3(32, 32, 5), 256, 0, stream>>>(Wq, Wk, Wv, Wo, WqT, WkT, WvT, WoT,
                                                         pe, Erl);

  gemm_qkv_kernel<<<dim3(DMODEL / 128, MTOK / 128, 3), 256, 0, stream>>>(
      qb, kb, vb, WqT, WkT, WvT, bq, bk, bv, Qp, Kp, Vp);

  attn_kernel<<<dim3(512, 1, 1), 512, 0, stream>>>(Qp, Kp, Vp, Erl, AOb);

  gemm_out_kernel<<<dim3(DMODEL / 128, MTOK / 128, 1), 512, 0, stream>>>(AOb, WoT, bo, out);
}

// Round 15
// 222.547 us; speedup vs baseline: 1.0542x; 1.0065x over previous
//
#include <hip/hip_runtime.h>

typedef unsigned short u16t;
typedef unsigned int   u32t;
typedef __bf16 bf16x8 __attribute__((ext_vector_type(8)));
typedef float  f32x4  __attribute__((ext_vector_type(4)));

#define NB     4
#define SEQ    1024
#define DMODEL 1024
#define NHEAD  16
#define DEPTH  64
#define MAXSEQ 2048
#define MTOK   (NB * SEQ)   // 4096 token rows

#define AS1 __attribute__((address_space(1)))
#define AS3 __attribute__((address_space(3)))

// f32 -> bf16 RNE via hw v_cvt (compiler packs pairs into v_cvt_pk_bf16_f32).
__device__ __forceinline__ u16t f2bf(float f) {
  return __builtin_bit_cast(u16t, (__bf16)f);
}
__device__ __forceinline__ float bf2f(u16t h) {
  return __builtin_bit_cast(float, (u32t)h << 16);
}
__device__ __forceinline__ void load_lds16(const void* g, void* l) {
  __builtin_amdgcn_global_load_lds((AS1 u32t*)(g), (AS3 u32t*)(l), 16, 0, 0);
}

// ---------------------------------------------------------------------------
// Prep kernels
// ---------------------------------------------------------------------------
__global__ void cvt3_kernel(const float* __restrict__ a, const float* __restrict__ b,
                            const float* __restrict__ c,
                            u16t* __restrict__ oa, u16t* __restrict__ ob,
                            u16t* __restrict__ oc, int n8) {
  int i = blockIdx.x * blockDim.x + threadIdx.x;
  if (i >= n8) return;
  const float* src = (blockIdx.z == 0) ? a : ((blockIdx.z == 1) ? b : c);
  u16t* dst = (blockIdx.z == 0) ? oa : ((blockIdx.z == 1) ? ob : oc);
  const float4* s4 = (const float4*)src;
  float4 x = s4[2 * i], y = s4[2 * i + 1];
  u16t tmp[8] = { f2bf(x.x), f2bf(x.y), f2bf(x.z), f2bf(x.w),
                  f2bf(y.x), f2bf(y.y), f2bf(y.z), f2bf(y.w) };
  ((uint4*)dst)[i] = *(const uint4*)tmp;
}

// z<4: WT[n][k] = bf16(W[k][n]).  z==4: Erel table Er[r][d]=bf16(pe[2047-r][d]).
__global__ void transpose4_kernel(const float* __restrict__ w0, const float* __restrict__ w1,
                                  const float* __restrict__ w2, const float* __restrict__ w3,
                                  u16t* __restrict__ t0, u16t* __restrict__ t1,
                                  u16t* __restrict__ t2, u16t* __restrict__ t3,
                                  const float* __restrict__ pe, u16t* __restrict__ Er) {
  const int z = blockIdx.z;
  if (z == 4) {
    const int flat = blockIdx.y * 32 + blockIdx.x;
    if (flat < 256) {
      const int idx = flat * 256 + threadIdx.x;     // SEQ*DEPTH = 65536
      const int r = idx >> 6, d = idx & 63;
      Er[idx] = f2bf(pe[(size_t)(MAXSEQ - 1 - r) * DEPTH + d]);
    }
    return;
  }
  const float* W = (z == 0) ? w0 : ((z == 1) ? w1 : ((z == 2) ? w2 : w3));
  u16t* WT = (z == 0) ? t0 : ((z == 1) ? t1 : ((z == 2) ? t2 : t3));
  __shared__ float tile[32][33];
  const int tx = threadIdx.x & 31, ty = threadIdx.x >> 5;   // 32x8
  const int bx = blockIdx.x * 32, by = blockIdx.y * 32;
#pragma unroll
  for (int r = 0; r < 32; r += 8)
    tile[ty + r][tx] = W[(size_t)(by + ty + r) * DMODEL + bx + tx];
  __syncthreads();
#pragma unroll
  for (int r = 0; r < 32; r += 8)
    WT[(size_t)(bx + ty + r) * DMODEL + by + tx] = f2bf(tile[tx][ty + r]);
}

// ---------------------------------------------------------------------------
// XCD-aware tile remap for (8 x 32) grids (verified: R7 gemm_qkv left top-5).
// ---------------------------------------------------------------------------
__device__ __forceinline__ void xcd_remap(int& bx, int& by) {
  const int flat = blockIdx.x + 8 * blockIdx.y;   // 0..255
  const int xv = flat & 7, pos = flat >> 3;       // xcd, 0..31
  bx = pos & 7;
  by = xv * 4 + (pos >> 3);
}

// ---------------------------------------------------------------------------
// QKV GEMM: C = (A(bf16) @ BT^T(bf16) + bias) * scale. m97-structure, kept:
// 3 blocks/CU -> implicit cross-block wave overlap already hides staging
// drains (guide m99/m100: explicit dbuf null in this regime).
// ---------------------------------------------------------------------------
__device__ __forceinline__ void gemm_bt_body(
    const u16t* __restrict__ A, const u16t* __restrict__ BT,
    const float* __restrict__ bias, u16t* __restrict__ C,
    int M, int Nc, int K, int bx, int by, float scale) {
  __shared__ __align__(16) u16t As[128 * 32];
  __shared__ __align__(16) u16t Bs[128 * 32];
  const int tid = threadIdx.x;
  const int wave = tid >> 6;
  const int lane = tid & 63;
  const int q = lane >> 4, t = lane & 15;
  const int lrow = lane >> 2, lch = lane & 3;
  const int bm = by * 128, bn = bx * 128;
  const int wi = (wave >> 1) * 64, wj = (wave & 1) * 64;

  f32x4 acc[4][4];
#pragma unroll
  for (int i = 0; i < 4; ++i)
#pragma unroll
    for (int j = 0; j < 4; ++j) acc[i][j] = f32x4{0.f, 0.f, 0.f, 0.f};

  for (int kt = 0; kt < K; kt += 32) {
    __syncthreads();
#pragma unroll
    for (int it = 0; it < 2; ++it) {
      const int rb = it * 64 + wave * 16;
      const u16t* ga = A + (size_t)(bm + rb + lrow) * K + kt + lch * 8;
      const u16t* gb = BT + (size_t)(bn + rb + lrow) * K + kt + lch * 8;
      load_lds16(ga, As + rb * 32);
      load_lds16(gb, Bs + rb * 32);
    }
    __syncthreads();
    bf16x8 af[4], bfr[4];
#pragma unroll
    for (int i = 0; i < 4; ++i) {
      af[i]  = *(const bf16x8*)(As + (wi + i * 16 + t) * 32 + q * 8);
      bfr[i] = *(const bf16x8*)(Bs + (wj + i * 16 + t) * 32 + q * 8);
    }
#pragma unroll
    for (int i = 0; i < 4; ++i)
#pragma unroll
      for (int j = 0; j < 4; ++j)
        acc[i][j] = __builtin_amdgcn_mfma_f32_16x16x32_bf16(af[i], bfr[j], acc[i][j], 0, 0, 0);
  }
#pragma unroll
  for (int j = 0; j < 4; ++j) {
    const int col = bn + wj + j * 16 + t;
    const float bv = bias[col];
#pragma unroll
    for (int i = 0; i < 4; ++i) {
#pragma unroll
      for (int r = 0; r < 4; ++r) {
        const int row = bm + wi + i * 16 + q * 4 + r;
        C[(size_t)row * Nc + col] = f2bf((acc[i][j][r] + bv) * scale);
      }
    }
  }
}

__global__ __launch_bounds__(256, 3) void gemm_qkv_kernel(
    const u16t* qa, const u16t* ka, const u16t* va,
    const u16t* wq, const u16t* wk, const u16t* wv,
    const float* bq, const float* bk, const float* bv,
    u16t* qo, u16t* ko, u16t* vo) {
  const int z = blockIdx.z;
  const u16t* A = (z == 0) ? qa : ((z == 1) ? ka : va);
  const u16t* B = (z == 0) ? wq : ((z == 1) ? wk : wv);
  const float* bb = (z == 0) ? bq : ((z == 1) ? bk : bv);
  u16t* C = (z == 0) ? qo : ((z == 1) ? ko : vo);
  const float scale = (z == 0) ? 0.125f : 1.0f;   // fold 1/sqrt(DEPTH) into Q
  int bx, by;
  xcd_remap(bx, by);
  gemm_bt_body(A, B, bb, C, MTOK, DMODEL, DMODEL, bx, by, scale);
}

// ---------------------------------------------------------------------------
// Output GEMM: 256 blocks = 1 block/CU, 2 waves/SIMD — NO cross-block
// implicit overlap, so the old stage->drain->compute loop exposed every
// global_load_lds latency at each of 32 barriers. THIS ROUND (T3-minimum
// 2-phase): double-buffered As/Bs (4x8 KB = 32 KB); per iter {issue next
// tile's stage into buf^1 BEFORE compute; ds_read+MFMA from buf[cur];
// one __syncthreads}. Prefetch latency (A=AOb, W: both L2/LLC-warm,
// ~200-400cy) hides under ~16 MFMA + 6 ds_read; barriers 64 -> 33.
// Safety: buf^1 last read in iter i-1, all waves passed i-1's barrier
// before the stage; reads of buf[cur] protected by i-1's barrier drain.
// ---------------------------------------------------------------------------
__global__ __launch_bounds__(512) void gemm_out_kernel(
    const u16t* __restrict__ A, const u16t* __restrict__ W,
    const float* __restrict__ bias, float* __restrict__ C) {
  __shared__ __align__(16) u16t As[2][128 * 32];
  __shared__ __align__(16) u16t Bs[2][128 * 32];
  const int tid = threadIdx.x;
  const int wave = tid >> 6, lane = tid & 63;
  const int q = lane >> 4, t = lane & 15;
  const int srow = wave * 16 + (lane >> 2);   // staging row 0..127
  const int sch = (lane & 3) * 8;             // staging k-offset
  int bx, by;
  xcd_remap(bx, by);
  const int bm = by * 128, bn = bx * 128;
  const int wi = (wave >> 1) * 32, wj = (wave & 1) * 64;
  const int K = DMODEL, Nc = DMODEL;
  const size_t arow = (size_t)(bm + srow) * K + sch;
  const size_t brow = (size_t)(bn + srow) * K + sch;

  f32x4 acc[2][4];
#pragma unroll
  for (int i = 0; i < 2; ++i)
#pragma unroll
    for (int j = 0; j < 4; ++j) acc[i][j] = f32x4{0.f, 0.f, 0.f, 0.f};

  // prologue: stage tile kt=0 into buf 0
  load_lds16(A + arow, As[0] + wave * 512);
  load_lds16(W + brow, Bs[0] + wave * 512);
  __syncthreads();

  for (int kt = 0; kt < K; kt += 32) {
    const int cur = (kt >> 5) & 1;
    // issue next tile's stage FIRST — overlaps with this tile's compute
    if (kt + 32 < K) {
      load_lds16(A + arow + kt + 32, As[cur ^ 1] + wave * 512);
      load_lds16(W + brow + kt + 32, Bs[cur ^ 1] + wave * 512);
    }
    bf16x8 af[2], bfr[4];
#pragma unroll
    for (int i = 0; i < 2; ++i)
      af[i] = *(const bf16x8*)(As[cur] + (wi + i * 16 + t) * 32 + q * 8);
#pragma unroll
    for (int j = 0; j < 4; ++j)
      bfr[j] = *(const bf16x8*)(Bs[cur] + (wj + j * 16 + t) * 32 + q * 8);
#pragma unroll
    for (int i = 0; i < 2; ++i)
#pragma unroll
      for (int j = 0; j < 4; ++j)
        acc[i][j] = __builtin_amdgcn_mfma_f32_16x16x32_bf16(af[i], bfr[j], acc[i][j], 0, 0, 0);
    __syncthreads();   // drains this iter's prefetch; buf^1 ready for next
  }
#pragma unroll
  for (int j = 0; j < 4; ++j) {
    const int col = bn + wj + j * 16 + t;
    const float bv = bias[col];
#pragma unroll
    for (int i = 0; i < 2; ++i) {
#pragma unroll
      for (int r = 0; r < 4; ++r) {
        const int row = bm + wi + i * 16 + q * 4 + r;
        C[(size_t)row * Nc + col] = acc[i][j][r] + bv;
      }
    }
  }
}

// ---------------------------------------------------------------------------
// Fused causal attention with relative-position bias — 128-row Q-tiles.
// == R10 kernel (session best; attn warm 46-49 us, run-to-run +/-3 us) ==
// R10 confirmed the binding resource is LDS instruction ISSUE (shuffle-based
// skew transfer: 62.6->46.1 us at identical conflict count).
// REVERTED experiments (kept for the record):
//  * R11 predicate-skips: skips only helped non-critical-path waves;
//    branches inside the unrolled Es/MFMA loop broke scheduling.
//  * R13 DPP-paired P-store (55.3, outside noise): cross-lane pair dependency
//    serialized the P-store behind BOTH lanes' exp chains; conflicts rose.
//  Lesson: remove LDS ops only when it adds NO new dependency/control flow.
// Structure: Es 256-slot delta-ring + Ks/Vt stride-72 + per-wave TP; bias
// skew via __shfl (R10); 2 barriers/iter; K/V/Es reg-prefetch; T5 setprio.
// Dispatch order: i-tiles {7,6,5,4} then {0,1,2,3}. Fixed-max softmax;
// Q pre-scaled by 0.125. LDS 73.7 KB -> 2 blocks/CU.
// ---------------------------------------------------------------------------
__global__ __launch_bounds__(512, 4) void attn_kernel(
    const u16t* __restrict__ Qp, const u16t* __restrict__ Kp,
    const u16t* __restrict__ Vp, const u16t* __restrict__ Er,
    u16t* __restrict__ AO) {
  const int gx = blockIdx.x;
  const int xcd = gx & 7, slot = gx >> 3;     // group pinned to XCD
  const int ghi = slot & 7, k4 = slot >> 3;   // k4 in [0,8)
  const int T = (k4 < 4) ? (7 - k4) : (k4 - 4);   // {7,6,5,4,0,1,2,3}
  const int g = (ghi << 3) | xcd;             // 0..63 = (n,h)
  const int n = g >> 4, h = g & 15;

  const int tid = threadIdx.x;
  const int wave = tid >> 6, lane = tid & 63;
  const int q = lane >> 4, t = lane & 15;
  const int rr = tid >> 3;          // 0..63 staging row
  const int c0 = (tid & 7) * 8;     // 0..56 staging d-offset

  __shared__ __align__(16) u16t Es[256 * 72];   // 36 KB delta-ring
  __shared__ __align__(16) u16t Ks[64 * 72];    // 9 KB
  __shared__ __align__(16) u16t Vt[64 * 72];    // 9 KB [d][j^swz], stride-72
  __shared__ __align__(16) u16t TP[8 * 1152];   // 18 KB per-wave P staging
  u16t* TPw = TP + wave * 1152;

  const int I0 = T * 128;
  const int iw = I0 + wave * 16;
  const int jmax = 2 * T + 1;

  const size_t qoff = ((size_t)(n * SEQ + iw + t)) * DMODEL + h * DEPTH;
  const bf16x8 qf0 = *(const bf16x8*)(Qp + qoff + q * 8);
  const bf16x8 qf1 = *(const bf16x8*)(Qp + qoff + 32 + q * 8);

  // ---- bias shuffle pattern: src lane + lo/hi select, per target row-reg r ----
  int srcl[4];
  bool sel_lo[4];
#pragma unroll
  for (int r = 0; r < 4; ++r) {
    const int u = q * 4 + r - 1 - t;
    srcl[r] = (q << 4) | (u & 15);
    sel_lo[r] = (u >= 0);
  }

  // ---- preload Es chunks 2T, 2T+1 (delta in [128T, 128T+128)) ----
  const uint4 epre0 = *(const uint4*)(Er + ((size_t)(2 * T) * 64 + rr) * DEPTH + c0);
  const uint4 epre1 = *(const uint4*)(Er + ((size_t)(2 * T + 1) * 64 + rr) * DEPTH + c0);
  // ---- iter-0 globals ----
  const size_t kvoff0 = ((size_t)(n * SEQ + rr)) * DMODEL + h * DEPTH + c0;   // J0=0
  uint4 kv = *(const uint4*)(Kp + kvoff0);
  uint4 vv = *(const uint4*)(Vp + kvoff0);
  // chunk 2T-1 (may be OOB-below for T=0: mapped guard, garbage masked)
  uint4 ev = *(const uint4*)(Er + ((ptrdiff_t)(2 * T - 1) * 64 + rr) * DEPTH + c0);

  *(uint4*)(Es + (((2 * T) & 3) * 64 + rr) * 72 + c0) = epre0;
  *(uint4*)(Es + (((2 * T + 1) & 3) * 64 + rr) * 72 + c0) = epre1;

  f32x4 o[4];
#pragma unroll
  for (int c = 0; c < 4; ++c) o[c] = f32x4{0.f, 0.f, 0.f, 0.f};
  float l_r[4] = {0.f, 0.f, 0.f, 0.f};

  for (int jt = 0; jt <= jmax; ++jt) {
    const int J0 = jt * 64;
    const int cnew = 2 * T - 1 - jt;          // chunk staged this iter

    __syncthreads();    // previous tile fully consumed
    // ---- stage K (stride-72), Es chunk (ring, stride-72), V (transposed) ----
    *(uint4*)(Ks + rr * 72 + c0) = kv;
    *(uint4*)(Es + ((cnew & 3) * 64 + rr) * 72 + c0) = ev;
    {
      const u16t* pv = (const u16t*)&vv;
#pragma unroll
      for (int uu = 0; uu < 8; ++uu) {
        const int d = c0 + uu;
        Vt[d * 72 + (rr ^ (((d >> 2) & 7) << 3))] = pv[uu];
      }
    }
    __syncthreads();

    // ---- prefetch next-iter globals (drain overlaps compute) ----
    if (jt < jmax) {
      const size_t kvoff = ((size_t)(n * SEQ + J0 + 64 + rr)) * DMODEL + h * DEPTH + c0;
      kv = *(const uint4*)(Kp + kvoff);
      vv = *(const uint4*)(Vp + kvoff);
      ev = *(const uint4*)(Er + ((ptrdiff_t)(cnew - 1) * 64 + rr) * DEPTH + c0);
    }

    // ---- QK^T (K frags from stride-72 LDS) ----
    __builtin_amdgcn_s_setprio(1);
    f32x4 s[4];
#pragma unroll
    for (int c = 0; c < 4; ++c) s[c] = f32x4{0.f, 0.f, 0.f, 0.f};
#pragma unroll
    for (int kk = 0; kk < 2; ++kk) {
      const bf16x8 qf = kk ? qf1 : qf0;
#pragma unroll
      for (int c = 0; c < 4; ++c) {
        const bf16x8 kf = *(const bf16x8*)(Ks + (c * 16 + t) * 72 + kk * 32 + q * 8);
        s[c] = __builtin_amdgcn_mfma_f32_16x16x32_bf16(qf, kf, s[c], 0, 0, 0);
      }
    }
    // ---- bias T = Q @ Es^T over this wave's 80-wide delta window ----
    const int D0 = iw - J0 - 63;   // delta of window col 0
    f32x4 tb[5];
#pragma unroll
    for (int cc = 0; cc < 5; ++cc) tb[cc] = f32x4{0.f, 0.f, 0.f, 0.f};
#pragma unroll
    for (int kk = 0; kk < 2; ++kk) {
      const bf16x8 qf = kk ? qf1 : qf0;
#pragma unroll
      for (int cc = 0; cc < 5; ++cc) {
        const int sl = (int)(((unsigned)(D0 + cc * 16 + t)) & 255u);
        const bf16x8 ef = *(const bf16x8*)(Es + sl * 72 + kk * 32 + q * 8);
        tb[cc] = __builtin_amdgcn_mfma_f32_16x16x32_bf16(qf, ef, tb[cc], 0, 0, 0);
      }
    }
    __builtin_amdgcn_s_setprio(0);

    // ---- skew transfer in-register: sh[cc][r] = tb[cc][r] from srcl[r] ----
    float sh[5][4];
#pragma unroll
    for (int cc = 0; cc < 5; ++cc)
#pragma unroll
      for (int r = 0; r < 4; ++r)
        sh[cc][r] = __shfl(tb[cc][r], srcl[r], 64);

    // ---- logits + causal mask + fixed-max softmax numerator ----
    const int dIJ = I0 - J0;
#pragma unroll
    for (int c = 0; c < 4; ++c) {
      const int jc = c * 16 + t;               // j - J0
#pragma unroll
      for (int r = 0; r < 4; ++r) {
        const int ic = wave * 16 + q * 4 + r;  // i - I0
        const float bias = sel_lo[r] ? sh[4 - c][r] : sh[3 - c][r];
        float lg = s[c][r] + bias;
        lg = (jc <= ic + dIJ) ? lg : -1e30f;
        const float pr = __expf(lg);
        s[c][r] = pr;
        l_r[r] += pr;
      }
    }
    // ---- P -> LDS in A-operand layout (same-wave order) ----
#pragma unroll
    for (int c = 0; c < 4; ++c)
#pragma unroll
      for (int r = 0; r < 4; ++r)
        TPw[(q * 4 + r) * 72 + c * 16 + t] = f2bf(s[c][r]);

    const bf16x8 pf0 = *(const bf16x8*)(TPw + t * 72 + q * 8);
    const bf16x8 pf1 = *(const bf16x8*)(TPw + t * 72 + 32 + q * 8);
    __builtin_amdgcn_s_setprio(1);
#pragma unroll
    for (int c2 = 0; c2 < 4; ++c2) {
      const int dd = c2 * 16 + t;
      const int sw = (dd >> 2) & 7;
      const bf16x8 v0 = *(const bf16x8*)(Vt + dd * 72 + ((0 + q) ^ sw) * 8);
      const bf16x8 v1 = *(const bf16x8*)(Vt + dd * 72 + ((4 + q) ^ sw) * 8);
      o[c2] = __builtin_amdgcn_mfma_f32_16x16x32_bf16(pf0, v0, o[c2], 0, 0, 0);
      o[c2] = __builtin_amdgcn_mfma_f32_16x16x32_bf16(pf1, v1, o[c2], 0, 0, 0);
    }
    __builtin_amdgcn_s_setprio(0);
  }

  // ---- epilogue: reduce l over the 16 t-lanes, normalize, store ----
#pragma unroll
  for (int r = 0; r < 4; ++r) {
    float lsum = l_r[r];
    lsum += __shfl_xor(lsum, 1, 64);
    lsum += __shfl_xor(lsum, 2, 64);
    lsum += __shfl_xor(lsum, 4, 64);
    lsum += __shfl_xor(lsum, 8, 64);
    const float inv = 1.f / lsum;
    const size_t obase = ((size_t)(n * SEQ + iw + q * 4 + r)) * DMODEL + h * DEPTH;
#pragma unroll
    for (int c2 = 0; c2 < 4; ++c2)
      AO[obase + c2 * 16 + t] = f2bf(o[c2][r] * inv);
  }
}

// ---------------------------------------------------------------------------
extern "C" void kernel_launch(void* const* d_in, const int* in_sizes, int n_in,
                              void* d_out, int out_size, void* d_ws, size_t ws_size,
                              hipStream_t stream) {
  const float* q_in = (const float*)d_in[0];
  const float* k_in = (const float*)d_in[1];
  const float* v_in = (const float*)d_in[2];
  // d_in[3] = mask (causal; analytic)
  const float* Wq = (const float*)d_in[4];
  const float* bq = (const float*)d_in[5];
  const float* Wk = (const float*)d_in[6];
  const float* bk = (const float*)d_in[7];
  const float* Wv = (const float*)d_in[8];
  const float* bv = (const float*)d_in[9];
  const float* Wo = (const float*)d_in[10];
  const float* bo = (const float*)d_in[11];
  const float* pe = (const float*)d_in[12];
  float* out = (float*)d_out;

  char* ws = (char*)d_ws;
  constexpr size_t MB = 1ull << 20;
  u16t* qb  = (u16t*)(ws);            // 8 MB [prep..qkv]
  u16t* kb  = (u16t*)(ws + 8 * MB);
  u16t* vb  = (u16t*)(ws + 16 * MB);
  u16t* Qp  = (u16t*)(ws + 24 * MB);
  u16t* Kp  = (u16t*)(ws + 32 * MB);
  u16t* Vp  = (u16t*)(ws + 40 * MB);
  u16t* AOb = (u16t*)(ws + 48 * MB);
  u16t* WqT = (u16t*)(ws + 56 * MB);
  u16t* WkT = (u16t*)(ws + 58 * MB);
  u16t* WvT = (u16t*)(ws + 60 * MB);
  u16t* WoT = (u16t*)(ws + 62 * MB);
  // Erel at +64MB+16KB: 16 KB mapped guard below (ring chunk reads reach
  // down to Erl-16KB for fully-masked windows), 128 KB table above.
  u16t* Erl = (u16t*)(ws + 64 * MB + 16 * 1024);

  const size_t SZA = (size_t)MTOK * DMODEL;
  const int n8 = (int)(SZA / 8);
  cvt3_kernel<<<dim3(n8 / 256, 1, 3), 256, 0, stream>>>(q_in, k_in, v_in, qb, kb, vb, n8);
  transpose4_kernel<<<dim3(32, 32, 5), 256, 0, stream>>>(Wq, Wk, Wv, Wo, WqT, WkT, WvT, WoT,
                                                         pe, Erl);

  gemm_qkv_kernel<<<dim3(DMODEL / 128, MTOK / 128, 3), 256, 0, stream>>>(
      qb, kb, vb, WqT, WkT, WvT, bq, bk, bv, Qp, Kp, Vp);

  attn_kernel<<<dim3(512, 1, 1), 512, 0, stream>>>(Qp, Kp, Vp, Erl, AOb);

  gemm_out_kernel<<<dim3(DMODEL / 128, MTOK / 128, 1), 512, 0, stream>>>(AOb, WoT, bo, out);
}

// Round 16
// 222.090 us; speedup vs baseline: 1.0564x; 1.0021x over previous
//
#include <hip/hip_runtime.h>

typedef unsigned short u16t;
typedef unsigned int   u32t;
typedef __bf16 bf16x8 __attribute__((ext_vector_type(8)));
typedef float  f32x4  __attribute__((ext_vector_type(4)));

#define NB     4
#define SEQ    1024
#define DMODEL 1024
#define NHEAD  16
#define DEPTH  64
#define MAXSEQ 2048
#define MTOK   (NB * SEQ)   // 4096 token rows

#define AS1 __attribute__((address_space(1)))
#define AS3 __attribute__((address_space(3)))

// f32 -> bf16 RNE via hw v_cvt (compiler packs pairs into v_cvt_pk_bf16_f32).
__device__ __forceinline__ u16t f2bf(float f) {
  return __builtin_bit_cast(u16t, (__bf16)f);
}
__device__ __forceinline__ float bf2f(u16t h) {
  return __builtin_bit_cast(float, (u32t)h << 16);
}
__device__ __forceinline__ void load_lds16(const void* g, void* l) {
  __builtin_amdgcn_global_load_lds((AS1 u32t*)(g), (AS3 u32t*)(l), 16, 0, 0);
}

// ---------------------------------------------------------------------------
// Prep kernels
// ---------------------------------------------------------------------------
__global__ void cvt3_kernel(const float* __restrict__ a, const float* __restrict__ b,
                            const float* __restrict__ c,
                            u16t* __restrict__ oa, u16t* __restrict__ ob,
                            u16t* __restrict__ oc, int n8) {
  int i = blockIdx.x * blockDim.x + threadIdx.x;
  if (i >= n8) return;
  const float* src = (blockIdx.z == 0) ? a : ((blockIdx.z == 1) ? b : c);
  u16t* dst = (blockIdx.z == 0) ? oa : ((blockIdx.z == 1) ? ob : oc);
  const float4* s4 = (const float4*)src;
  float4 x = s4[2 * i], y = s4[2 * i + 1];
  u16t tmp[8] = { f2bf(x.x), f2bf(x.y), f2bf(x.z), f2bf(x.w),
                  f2bf(y.x), f2bf(y.y), f2bf(y.z), f2bf(y.w) };
  ((uint4*)dst)[i] = *(const uint4*)tmp;
}

// z<4: WT[n][k] = bf16(W[k][n]).  z==4: Erel table Er[r][d]=bf16(pe[2047-r][d]).
__global__ void transpose4_kernel(const float* __restrict__ w0, const float* __restrict__ w1,
                                  const float* __restrict__ w2, const float* __restrict__ w3,
                                  u16t* __restrict__ t0, u16t* __restrict__ t1,
                                  u16t* __restrict__ t2, u16t* __restrict__ t3,
                                  const float* __restrict__ pe, u16t* __restrict__ Er) {
  const int z = blockIdx.z;
  if (z == 4) {
    const int flat = blockIdx.y * 32 + blockIdx.x;
    if (flat < 256) {
      const int idx = flat * 256 + threadIdx.x;     // SEQ*DEPTH = 65536
      const int r = idx >> 6, d = idx & 63;
      Er[idx] = f2bf(pe[(size_t)(MAXSEQ - 1 - r) * DEPTH + d]);
    }
    return;
  }
  const float* W = (z == 0) ? w0 : ((z == 1) ? w1 : ((z == 2) ? w2 : w3));
  u16t* WT = (z == 0) ? t0 : ((z == 1) ? t1 : ((z == 2) ? t2 : t3));
  __shared__ float tile[32][33];
  const int tx = threadIdx.x & 31, ty = threadIdx.x >> 5;   // 32x8
  const int bx = blockIdx.x * 32, by = blockIdx.y * 32;
#pragma unroll
  for (int r = 0; r < 32; r += 8)
    tile[ty + r][tx] = W[(size_t)(by + ty + r) * DMODEL + bx + tx];
  __syncthreads();
#pragma unroll
  for (int r = 0; r < 32; r += 8)
    WT[(size_t)(bx + ty + r) * DMODEL + by + tx] = f2bf(tile[tx][ty + r]);
}

// ---------------------------------------------------------------------------
// XCD-aware tile remap for (8 x 32) grids (verified: R7 gemm_qkv left top-5).
// ---------------------------------------------------------------------------
__device__ __forceinline__ void xcd_remap(int& bx, int& by) {
  const int flat = blockIdx.x + 8 * blockIdx.y;   // 0..255
  const int xv = flat & 7, pos = flat >> 3;       // xcd, 0..31
  bx = pos & 7;
  by = xv * 4 + (pos >> 3);
}

// ---------------------------------------------------------------------------
// QKV GEMM: C = (A(bf16) @ BT^T(bf16) + bias) * scale.
// R16: BK=64 via TWO BK=32 panels. The proven [128][32] per-panel layout and
// frag-read pattern are bit-identical (naive [128][64] would put frag rows at
// stride 128B == 0 mod 32 banks -> 16-way conflict, and padding breaks
// global_load_lds). Stage both panels (8 loads/thread), ONE barrier pair per
// 64-K: barriers 64 -> 32, each vmcnt(0) drain amortized over 2x MFMA.
// LDS 32 KB -> still 3 blocks/CU (96 KB).
// ---------------------------------------------------------------------------
__device__ __forceinline__ void gemm_bt_body(
    const u16t* __restrict__ A, const u16t* __restrict__ BT,
    const float* __restrict__ bias, u16t* __restrict__ C,
    int M, int Nc, int K, int bx, int by, float scale) {
  __shared__ __align__(16) u16t As[2][128 * 32];
  __shared__ __align__(16) u16t Bs[2][128 * 32];
  const int tid = threadIdx.x;
  const int wave = tid >> 6;
  const int lane = tid & 63;
  const int q = lane >> 4, t = lane & 15;
  const int lrow = lane >> 2, lch = lane & 3;
  const int bm = by * 128, bn = bx * 128;
  const int wi = (wave >> 1) * 64, wj = (wave & 1) * 64;

  f32x4 acc[4][4];
#pragma unroll
  for (int i = 0; i < 4; ++i)
#pragma unroll
    for (int j = 0; j < 4; ++j) acc[i][j] = f32x4{0.f, 0.f, 0.f, 0.f};

  for (int kt = 0; kt < K; kt += 64) {
    __syncthreads();
#pragma unroll
    for (int half = 0; half < 2; ++half) {
#pragma unroll
      for (int it = 0; it < 2; ++it) {
        const int rb = it * 64 + wave * 16;
        const u16t* ga = A + (size_t)(bm + rb + lrow) * K + kt + half * 32 + lch * 8;
        const u16t* gb = BT + (size_t)(bn + rb + lrow) * K + kt + half * 32 + lch * 8;
        load_lds16(ga, As[half] + rb * 32);
        load_lds16(gb, Bs[half] + rb * 32);
      }
    }
    __syncthreads();
#pragma unroll
    for (int half = 0; half < 2; ++half) {
      bf16x8 af[4], bfr[4];
#pragma unroll
      for (int i = 0; i < 4; ++i) {
        af[i]  = *(const bf16x8*)(As[half] + (wi + i * 16 + t) * 32 + q * 8);
        bfr[i] = *(const bf16x8*)(Bs[half] + (wj + i * 16 + t) * 32 + q * 8);
      }
#pragma unroll
      for (int i = 0; i < 4; ++i)
#pragma unroll
        for (int j = 0; j < 4; ++j)
          acc[i][j] = __builtin_amdgcn_mfma_f32_16x16x32_bf16(af[i], bfr[j], acc[i][j], 0, 0, 0);
    }
  }
#pragma unroll
  for (int j = 0; j < 4; ++j) {
    const int col = bn + wj + j * 16 + t;
    const float bv = bias[col];
#pragma unroll
    for (int i = 0; i < 4; ++i) {
#pragma unroll
      for (int r = 0; r < 4; ++r) {
        const int row = bm + wi + i * 16 + q * 4 + r;
        C[(size_t)row * Nc + col] = f2bf((acc[i][j][r] + bv) * scale);
      }
    }
  }
}

__global__ __launch_bounds__(256, 3) void gemm_qkv_kernel(
    const u16t* qa, const u16t* ka, const u16t* va,
    const u16t* wq, const u16t* wk, const u16t* wv,
    const float* bq, const float* bk, const float* bv,
    u16t* qo, u16t* ko, u16t* vo) {
  const int z = blockIdx.z;
  const u16t* A = (z == 0) ? qa : ((z == 1) ? ka : va);
  const u16t* B = (z == 0) ? wq : ((z == 1) ? wk : wv);
  const float* bb = (z == 0) ? bq : ((z == 1) ? bk : bv);
  u16t* C = (z == 0) ? qo : ((z == 1) ? ko : vo);
  const float scale = (z == 0) ? 0.125f : 1.0f;   // fold 1/sqrt(DEPTH) into Q
  int bx, by;
  xcd_remap(bx, by);
  gemm_bt_body(A, B, bb, C, MTOK, DMODEL, DMODEL, bx, by, scale);
}

// ---------------------------------------------------------------------------
// Output GEMM: 256 blocks = 1 block/CU, 2-phase double-buffer (R15: -1.5 us
// total, kept). Issue next tile's stage BEFORE compute; one barrier/iter.
// ---------------------------------------------------------------------------
__global__ __launch_bounds__(512) void gemm_out_kernel(
    const u16t* __restrict__ A, const u16t* __restrict__ W,
    const float* __restrict__ bias, float* __restrict__ C) {
  __shared__ __align__(16) u16t As[2][128 * 32];
  __shared__ __align__(16) u16t Bs[2][128 * 32];
  const int tid = threadIdx.x;
  const int wave = tid >> 6, lane = tid & 63;
  const int q = lane >> 4, t = lane & 15;
  const int srow = wave * 16 + (lane >> 2);   // staging row 0..127
  const int sch = (lane & 3) * 8;             // staging k-offset
  int bx, by;
  xcd_remap(bx, by);
  const int bm = by * 128, bn = bx * 128;
  const int wi = (wave >> 1) * 32, wj = (wave & 1) * 64;
  const int K = DMODEL, Nc = DMODEL;
  const size_t arow = (size_t)(bm + srow) * K + sch;
  const size_t brow = (size_t)(bn + srow) * K + sch;

  f32x4 acc[2][4];
#pragma unroll
  for (int i = 0; i < 2; ++i)
#pragma unroll
    for (int j = 0; j < 4; ++j) acc[i][j] = f32x4{0.f, 0.f, 0.f, 0.f};

  // prologue: stage tile kt=0 into buf 0
  load_lds16(A + arow, As[0] + wave * 512);
  load_lds16(W + brow, Bs[0] + wave * 512);
  __syncthreads();

  for (int kt = 0; kt < K; kt += 32) {
    const int cur = (kt >> 5) & 1;
    // issue next tile's stage FIRST — overlaps with this tile's compute
    if (kt + 32 < K) {
      load_lds16(A + arow + kt + 32, As[cur ^ 1] + wave * 512);
      load_lds16(W + brow + kt + 32, Bs[cur ^ 1] + wave * 512);
    }
    bf16x8 af[2], bfr[4];
#pragma unroll
    for (int i = 0; i < 2; ++i)
      af[i] = *(const bf16x8*)(As[cur] + (wi + i * 16 + t) * 32 + q * 8);
#pragma unroll
    for (int j = 0; j < 4; ++j)
      bfr[j] = *(const bf16x8*)(Bs[cur] + (wj + j * 16 + t) * 32 + q * 8);
#pragma unroll
    for (int i = 0; i < 2; ++i)
#pragma unroll
      for (int j = 0; j < 4; ++j)
        acc[i][j] = __builtin_amdgcn_mfma_f32_16x16x32_bf16(af[i], bfr[j], acc[i][j], 0, 0, 0);
    __syncthreads();   // drains this iter's prefetch; buf^1 ready for next
  }
#pragma unroll
  for (int j = 0; j < 4; ++j) {
    const int col = bn + wj + j * 16 + t;
    const float bv = bias[col];
#pragma unroll
    for (int i = 0; i < 2; ++i) {
#pragma unroll
      for (int r = 0; r < 4; ++r) {
        const int row = bm + wi + i * 16 + q * 4 + r;
        C[(size_t)row * Nc + col] = acc[i][j][r] + bv;
      }
    }
  }
}

// ---------------------------------------------------------------------------
// Fused causal attention with relative-position bias — 128-row Q-tiles.
// == R10 kernel (session best; attn warm 46-49 us, run-to-run +/-1.5 us) ==
// Binding resource: LDS instruction ISSUE (R10: shuffle skew 62.6->46.1 at
// identical conflict count). Reverted: R11 predicate-skips (branches broke
// scheduling), R13 DPP-paired P-store (new cross-lane dependency serialized).
// Lesson: remove LDS ops only when it adds NO new dependency/control flow.
// Structure: Es 256-slot delta-ring + Ks/Vt stride-72 + per-wave TP; bias
// skew via __shfl; 2 barriers/iter; K/V/Es reg-prefetch; T5 setprio.
// Dispatch order: i-tiles {7,6,5,4} then {0,1,2,3}. Fixed-max softmax;
// Q pre-scaled by 0.125. LDS 73.7 KB -> 2 blocks/CU.
// ---------------------------------------------------------------------------
__global__ __launch_bounds__(512, 4) void attn_kernel(
    const u16t* __restrict__ Qp, const u16t* __restrict__ Kp,
    const u16t* __restrict__ Vp, const u16t* __restrict__ Er,
    u16t* __restrict__ AO) {
  const int gx = blockIdx.x;
  const int xcd = gx & 7, slot = gx >> 3;     // group pinned to XCD
  const int ghi = slot & 7, k4 = slot >> 3;   // k4 in [0,8)
  const int T = (k4 < 4) ? (7 - k4) : (k4 - 4);   // {7,6,5,4,0,1,2,3}
  const int g = (ghi << 3) | xcd;             // 0..63 = (n,h)
  const int n = g >> 4, h = g & 15;

  const int tid = threadIdx.x;
  const int wave = tid >> 6, lane = tid & 63;
  const int q = lane >> 4, t = lane & 15;
  const int rr = tid >> 3;          // 0..63 staging row
  const int c0 = (tid & 7) * 8;     // 0..56 staging d-offset

  __shared__ __align__(16) u16t Es[256 * 72];   // 36 KB delta-ring
  __shared__ __align__(16) u16t Ks[64 * 72];    // 9 KB
  __shared__ __align__(16) u16t Vt[64 * 72];    // 9 KB [d][j^swz], stride-72
  __shared__ __align__(16) u16t TP[8 * 1152];   // 18 KB per-wave P staging
  u16t* TPw = TP + wave * 1152;

  const int I0 = T * 128;
  const int iw = I0 + wave * 16;
  const int jmax = 2 * T + 1;

  const size_t qoff = ((size_t)(n * SEQ + iw + t)) * DMODEL + h * DEPTH;
  const bf16x8 qf0 = *(const bf16x8*)(Qp + qoff + q * 8);
  const bf16x8 qf1 = *(const bf16x8*)(Qp + qoff + 32 + q * 8);

  // ---- bias shuffle pattern: src lane + lo/hi select, per target row-reg r ----
  int srcl[4];
  bool sel_lo[4];
#pragma unroll
  for (int r = 0; r < 4; ++r) {
    const int u = q * 4 + r - 1 - t;
    srcl[r] = (q << 4) | (u & 15);
    sel_lo[r] = (u >= 0);
  }

  // ---- preload Es chunks 2T, 2T+1 (delta in [128T, 128T+128)) ----
  const uint4 epre0 = *(const uint4*)(Er + ((size_t)(2 * T) * 64 + rr) * DEPTH + c0);
  const uint4 epre1 = *(const uint4*)(Er + ((size_t)(2 * T + 1) * 64 + rr) * DEPTH + c0);
  // ---- iter-0 globals ----
  const size_t kvoff0 = ((size_t)(n * SEQ + rr)) * DMODEL + h * DEPTH + c0;   // J0=0
  uint4 kv = *(const uint4*)(Kp + kvoff0);
  uint4 vv = *(const uint4*)(Vp + kvoff0);
  // chunk 2T-1 (may be OOB-below for T=0: mapped guard, garbage masked)
  uint4 ev = *(const uint4*)(Er + ((ptrdiff_t)(2 * T - 1) * 64 + rr) * DEPTH + c0);

  *(uint4*)(Es + (((2 * T) & 3) * 64 + rr) * 72 + c0) = epre0;
  *(uint4*)(Es + (((2 * T + 1) & 3) * 64 + rr) * 72 + c0) = epre1;

  f32x4 o[4];
#pragma unroll
  for (int c = 0; c < 4; ++c) o[c] = f32x4{0.f, 0.f, 0.f, 0.f};
  float l_r[4] = {0.f, 0.f, 0.f, 0.f};

  for (int jt = 0; jt <= jmax; ++jt) {
    const int J0 = jt * 64;
    const int cnew = 2 * T - 1 - jt;          // chunk staged this iter

    __syncthreads();    // previous tile fully consumed
    // ---- stage K (stride-72), Es chunk (ring, stride-72), V (transposed) ----
    *(uint4*)(Ks + rr * 72 + c0) = kv;
    *(uint4*)(Es + ((cnew & 3) * 64 + rr) * 72 + c0) = ev;
    {
      const u16t* pv = (const u16t*)&vv;
#pragma unroll
      for (int uu = 0; uu < 8; ++uu) {
        const int d = c0 + uu;
        Vt[d * 72 + (rr ^ (((d >> 2) & 7) << 3))] = pv[uu];
      }
    }
    __syncthreads();

    // ---- prefetch next-iter globals (drain overlaps compute) ----
    if (jt < jmax) {
      const size_t kvoff = ((size_t)(n * SEQ + J0 + 64 + rr)) * DMODEL + h * DEPTH + c0;
      kv = *(const uint4*)(Kp + kvoff);
      vv = *(const uint4*)(Vp + kvoff);
      ev = *(const uint4*)(Er + ((ptrdiff_t)(cnew - 1) * 64 + rr) * DEPTH + c0);
    }

    // ---- QK^T (K frags from stride-72 LDS) ----
    __builtin_amdgcn_s_setprio(1);
    f32x4 s[4];
#pragma unroll
    for (int c = 0; c < 4; ++c) s[c] = f32x4{0.f, 0.f, 0.f, 0.f};
#pragma unroll
    for (int kk = 0; kk < 2; ++kk) {
      const bf16x8 qf = kk ? qf1 : qf0;
#pragma unroll
      for (int c = 0; c < 4; ++c) {
        const bf16x8 kf = *(const bf16x8*)(Ks + (c * 16 + t) * 72 + kk * 32 + q * 8);
        s[c] = __builtin_amdgcn_mfma_f32_16x16x32_bf16(qf, kf, s[c], 0, 0, 0);
      }
    }
    // ---- bias T = Q @ Es^T over this wave's 80-wide delta window ----
    const int D0 = iw - J0 - 63;   // delta of window col 0
    f32x4 tb[5];
#pragma unroll
    for (int cc = 0; cc < 5; ++cc) tb[cc] = f32x4{0.f, 0.f, 0.f, 0.f};
#pragma unroll
    for (int kk = 0; kk < 2; ++kk) {
      const bf16x8 qf = kk ? qf1 : qf0;
#pragma unroll
      for (int cc = 0; cc < 5; ++cc) {
        const int sl = (int)(((unsigned)(D0 + cc * 16 + t)) & 255u);
        const bf16x8 ef = *(const bf16x8*)(Es + sl * 72 + kk * 32 + q * 8);
        tb[cc] = __builtin_amdgcn_mfma_f32_16x16x32_bf16(qf, ef, tb[cc], 0, 0, 0);
      }
    }
    __builtin_amdgcn_s_setprio(0);

    // ---- skew transfer in-register: sh[cc][r] = tb[cc][r] from srcl[r] ----
    float sh[5][4];
#pragma unroll
    for (int cc = 0; cc < 5; ++cc)
#pragma unroll
      for (int r = 0; r < 4; ++r)
        sh[cc][r] = __shfl(tb[cc][r], srcl[r], 64);

    // ---- logits + causal mask + fixed-max softmax numerator ----
    const int dIJ = I0 - J0;
#pragma unroll
    for (int c = 0; c < 4; ++c) {
      const int jc = c * 16 + t;               // j - J0
#pragma unroll
      for (int r = 0; r < 4; ++r) {
        const int ic = wave * 16 + q * 4 + r;  // i - I0
        const float bias = sel_lo[r] ? sh[4 - c][r] : sh[3 - c][r];
        float lg = s[c][r] + bias;
        lg = (jc <= ic + dIJ) ? lg : -1e30f;
        const float pr = __expf(lg);
        s[c][r] = pr;
        l_r[r] += pr;
      }
    }
    // ---- P -> LDS in A-operand layout (same-wave order) ----
#pragma unroll
    for (int c = 0; c < 4; ++c)
#pragma unroll
      for (int r = 0; r < 4; ++r)
        TPw[(q * 4 + r) * 72 + c * 16 + t] = f2bf(s[c][r]);

    const bf16x8 pf0 = *(const bf16x8*)(TPw + t * 72 + q * 8);
    const bf16x8 pf1 = *(const bf16x8*)(TPw + t * 72 + 32 + q * 8);
    __builtin_amdgcn_s_setprio(1);
#pragma unroll
    for (int c2 = 0; c2 < 4; ++c2) {
      const int dd = c2 * 16 + t;
      const int sw = (dd >> 2) & 7;
      const bf16x8 v0 = *(const bf16x8*)(Vt + dd * 72 + ((0 + q) ^ sw) * 8);
      const bf16x8 v1 = *(const bf16x8*)(Vt + dd * 72 + ((4 + q) ^ sw) * 8);
      o[c2] = __builtin_amdgcn_mfma_f32_16x16x32_bf16(pf0, v0, o[c2], 0, 0, 0);
      o[c2] = __builtin_amdgcn_mfma_f32_16x16x32_bf16(pf1, v1, o[c2], 0, 0, 0);
    }
    __builtin_amdgcn_s_setprio(0);
  }

  // ---- epilogue: reduce l over the 16 t-lanes, normalize, store ----
#pragma unroll
  for (int r = 0; r < 4; ++r) {
    float lsum = l_r[r];
    lsum += __shfl_xor(lsum, 1, 64);
    lsum += __shfl_xor(lsum, 2, 64);
    lsum += __shfl_xor(lsum, 4, 64);
    lsum += __shfl_xor(lsum, 8, 64);
    const float inv = 1.f / lsum;
    const size_t obase = ((size_t)(n * SEQ + iw + q * 4 + r)) * DMODEL + h * DEPTH;
#pragma unroll
    for (int c2 = 0; c2 < 4; ++c2)
      AO[obase + c2 * 16 + t] = f2bf(o[c2][r] * inv);
  }
}

// ---------------------------------------------------------------------------
extern "C" void kernel_launch(void* const* d_in, const int* in_sizes, int n_in,
                              void* d_out, int out_size, void* d_ws, size_t ws_size,
                              hipStream_t stream) {
  const float* q_in = (const float*)d_in[0];
  const float* k_in = (const float*)d_in[1];
  const float* v_in = (const float*)d_in[2];
  // d_in[3] = mask (causal; analytic)
  const float* Wq = (const float*)d_in[4];
  const float* bq = (const float*)d_in[5];
  const float* Wk = (const float*)d_in[6];
  const float* bk = (const float*)d_in[7];
  const float* Wv = (const float*)d_in[8];
  const float* bv = (const float*)d_in[9];
  const float* Wo = (const float*)d_in[10];
  const float* bo = (const float*)d_in[11];
  const float* pe = (const float*)d_in[12];
  float* out = (float*)d_out;

  char* ws = (char*)d_ws;
  constexpr size_t MB = 1ull << 20;
  u16t* qb  = (u16t*)(ws);            // 8 MB [prep..qkv]
  u16t* kb  = (u16t*)(ws + 8 * MB);
  u16t* vb  = (u16t*)(ws + 16 * MB);
  u16t* Qp  = (u16t*)(ws + 24 * MB);
  u16t* Kp  = (u16t*)(ws + 32 * MB);
  u16t* Vp  = (u16t*)(ws + 40 * MB);
  u16t* AOb = (u16t*)(ws + 48 * MB);
  u16t* WqT = (u16t*)(ws + 56 * MB);
  u16t* WkT = (u16t*)(ws + 58 * MB);
  u16t* WvT = (u16t*)(ws + 60 * MB);
  u16t* WoT = (u16t*)(ws + 62 * MB);
  // Erel at +64MB+16KB: 16 KB mapped guard below (ring chunk reads reach
  // down to Erl-16KB for fully-masked windows), 128 KB table above.
  u16t* Erl = (u16t*)(ws + 64 * MB + 16 * 1024);

  const size_t SZA = (size_t)MTOK * DMODEL;
  const int n8 = (int)(SZA / 8);
  cvt3_kernel<<<dim3(n8 / 256, 1, 3), 256, 0, stream>>>(q_in, k_in, v_in, qb, kb, vb, n8);
  transpose4_kernel<<<dim3(32, 32, 5), 256, 0, stream>>>(Wq, Wk, Wv, Wo, WqT, WkT, WvT, WoT,
                                                         pe, Erl);

  gemm_qkv_kernel<<<dim3(DMODEL / 128, MTOK / 128, 3), 256, 0, stream>>>(
      qb, kb, vb, WqT, WkT, WvT, bq, bk, bv, Qp, Kp, Vp);

  attn_kernel<<<dim3(512, 1, 1), 512, 0, stream>>>(Qp, Kp, Vp, Erl, AOb);

  gemm_out_kernel<<<dim3(DMODEL / 128, MTOK / 128, 1), 512, 0, stream>>>(AOb, WoT, bo, out);
}

// Round 17
// 221.503 us; speedup vs baseline: 1.0592x; 1.0027x over previous
//
#include <hip/hip_runtime.h>

typedef unsigned short u16t;
typedef unsigned int   u32t;
typedef __bf16 bf16x8 __attribute__((ext_vector_type(8)));
typedef float  f32x4  __attribute__((ext_vector_type(4)));

#define NB     4
#define SEQ    1024
#define DMODEL 1024
#define NHEAD  16
#define DEPTH  64
#define MAXSEQ 2048
#define MTOK   (NB * SEQ)   // 4096 token rows

#define AS1 __attribute__((address_space(1)))
#define AS3 __attribute__((address_space(3)))

// f32 -> bf16 RNE via hw v_cvt (compiler packs pairs into v_cvt_pk_bf16_f32).
__device__ __forceinline__ u16t f2bf(float f) {
  return __builtin_bit_cast(u16t, (__bf16)f);
}
__device__ __forceinline__ float bf2f(u16t h) {
  return __builtin_bit_cast(float, (u32t)h << 16);
}
__device__ __forceinline__ void load_lds16(const void* g, void* l) {
  __builtin_amdgcn_global_load_lds((AS1 u32t*)(g), (AS3 u32t*)(l), 16, 0, 0);
}

// ---------------------------------------------------------------------------
// Fused prep kernel: z<3 = f32->bf16 cvt of q/k/v (grid-x guarded by n8);
// z==3 = transpose4 work flattened (zz = x>>10: 0..3 weight transposes,
// 4 = Erel table). Merging removes one launch AND lets the small transpose
// run concurrently under cvt's BW-bound streaming (same stream previously
// serialized them: ~4 us + gap of pure serialization).
// ---------------------------------------------------------------------------
__global__ void prep_kernel(const float* __restrict__ a, const float* __restrict__ b,
                            const float* __restrict__ c,
                            u16t* __restrict__ oa, u16t* __restrict__ ob,
                            u16t* __restrict__ oc, int n8,
                            const float* __restrict__ w0, const float* __restrict__ w1,
                            const float* __restrict__ w2, const float* __restrict__ w3,
                            u16t* __restrict__ t0, u16t* __restrict__ t1,
                            u16t* __restrict__ t2, u16t* __restrict__ t3,
                            const float* __restrict__ pe, u16t* __restrict__ Er) {
  const int z = blockIdx.z;
  if (z < 3) {
    const int i = blockIdx.x * blockDim.x + threadIdx.x;
    if (i >= n8) return;
    const float* src = (z == 0) ? a : ((z == 1) ? b : c);
    u16t* dst = (z == 0) ? oa : ((z == 1) ? ob : oc);
    const float4* s4 = (const float4*)src;
    float4 x = s4[2 * i], y = s4[2 * i + 1];
    u16t tmp[8] = { f2bf(x.x), f2bf(x.y), f2bf(x.z), f2bf(x.w),
                    f2bf(y.x), f2bf(y.y), f2bf(y.z), f2bf(y.w) };
    ((uint4*)dst)[i] = *(const uint4*)tmp;
    return;
  }
  // z == 3: transpose plane. blk in [0, 5120): zz = weight index / Er plane.
  const int blk = blockIdx.x;
  const int zz = blk >> 10;           // 0..4
  const int rem = blk & 1023;
  if (zz == 4) {
    if (rem < 256) {
      const int idx = rem * 256 + threadIdx.x;     // SEQ*DEPTH = 65536
      const int r = idx >> 6, d = idx & 63;
      Er[idx] = f2bf(pe[(size_t)(MAXSEQ - 1 - r) * DEPTH + d]);
    }
    return;
  }
  const float* W = (zz == 0) ? w0 : ((zz == 1) ? w1 : ((zz == 2) ? w2 : w3));
  u16t* WT = (zz == 0) ? t0 : ((zz == 1) ? t1 : ((zz == 2) ? t2 : t3));
  __shared__ float tile[32][33];
  const int tx = threadIdx.x & 31, ty = threadIdx.x >> 5;   // 32x8
  const int bx = (rem & 31) * 32, by = (rem >> 5) * 32;
#pragma unroll
  for (int r = 0; r < 32; r += 8)
    tile[ty + r][tx] = W[(size_t)(by + ty + r) * DMODEL + bx + tx];
  __syncthreads();
#pragma unroll
  for (int r = 0; r < 32; r += 8)
    WT[(size_t)(bx + ty + r) * DMODEL + by + tx] = f2bf(tile[tx][ty + r]);
}

// ---------------------------------------------------------------------------
// XCD-aware tile remap for (8 x 32) grids (verified: R7 gemm_qkv left top-5).
// ---------------------------------------------------------------------------
__device__ __forceinline__ void xcd_remap(int& bx, int& by) {
  const int flat = blockIdx.x + 8 * blockIdx.y;   // 0..255
  const int xv = flat & 7, pos = flat >> 3;       // xcd, 0..31
  bx = pos & 7;
  by = xv * 4 + (pos >> 3);
}

// ---------------------------------------------------------------------------
// QKV GEMM: C = (A(bf16) @ BT^T(bf16) + bias) * scale.
// BK=64 via TWO BK=32 panels (R16, kept): proven [128][32] per-panel layout
// bit-identical; barriers 64 -> 32, each vmcnt(0) drain amortized over 2x
// MFMA. LDS 32 KB -> still 3 blocks/CU.
// ---------------------------------------------------------------------------
__device__ __forceinline__ void gemm_bt_body(
    const u16t* __restrict__ A, const u16t* __restrict__ BT,
    const float* __restrict__ bias, u16t* __restrict__ C,
    int M, int Nc, int K, int bx, int by, float scale) {
  __shared__ __align__(16) u16t As[2][128 * 32];
  __shared__ __align__(16) u16t Bs[2][128 * 32];
  const int tid = threadIdx.x;
  const int wave = tid >> 6;
  const int lane = tid & 63;
  const int q = lane >> 4, t = lane & 15;
  const int lrow = lane >> 2, lch = lane & 3;
  const int bm = by * 128, bn = bx * 128;
  const int wi = (wave >> 1) * 64, wj = (wave & 1) * 64;

  f32x4 acc[4][4];
#pragma unroll
  for (int i = 0; i < 4; ++i)
#pragma unroll
    for (int j = 0; j < 4; ++j) acc[i][j] = f32x4{0.f, 0.f, 0.f, 0.f};

  for (int kt = 0; kt < K; kt += 64) {
    __syncthreads();
#pragma unroll
    for (int half = 0; half < 2; ++half) {
#pragma unroll
      for (int it = 0; it < 2; ++it) {
        const int rb = it * 64 + wave * 16;
        const u16t* ga = A + (size_t)(bm + rb + lrow) * K + kt + half * 32 + lch * 8;
        const u16t* gb = BT + (size_t)(bn + rb + lrow) * K + kt + half * 32 + lch * 8;
        load_lds16(ga, As[half] + rb * 32);
        load_lds16(gb, Bs[half] + rb * 32);
      }
    }
    __syncthreads();
#pragma unroll
    for (int half = 0; half < 2; ++half) {
      bf16x8 af[4], bfr[4];
#pragma unroll
      for (int i = 0; i < 4; ++i) {
        af[i]  = *(const bf16x8*)(As[half] + (wi + i * 16 + t) * 32 + q * 8);
        bfr[i] = *(const bf16x8*)(Bs[half] + (wj + i * 16 + t) * 32 + q * 8);
      }
#pragma unroll
      for (int i = 0; i < 4; ++i)
#pragma unroll
        for (int j = 0; j < 4; ++j)
          acc[i][j] = __builtin_amdgcn_mfma_f32_16x16x32_bf16(af[i], bfr[j], acc[i][j], 0, 0, 0);
    }
  }
#pragma unroll
  for (int j = 0; j < 4; ++j) {
    const int col = bn + wj + j * 16 + t;
    const float bv = bias[col];
#pragma unroll
    for (int i = 0; i < 4; ++i) {
#pragma unroll
      for (int r = 0; r < 4; ++r) {
        const int row = bm + wi + i * 16 + q * 4 + r;
        C[(size_t)row * Nc + col] = f2bf((acc[i][j][r] + bv) * scale);
      }
    }
  }
}

__global__ __launch_bounds__(256, 3) void gemm_qkv_kernel(
    const u16t* qa, const u16t* ka, const u16t* va,
    const u16t* wq, const u16t* wk, const u16t* wv,
    const float* bq, const float* bk, const float* bv,
    u16t* qo, u16t* ko, u16t* vo) {
  const int z = blockIdx.z;
  const u16t* A = (z == 0) ? qa : ((z == 1) ? ka : va);
  const u16t* B = (z == 0) ? wq : ((z == 1) ? wk : wv);
  const float* bb = (z == 0) ? bq : ((z == 1) ? bk : bv);
  u16t* C = (z == 0) ? qo : ((z == 1) ? ko : vo);
  const float scale = (z == 0) ? 0.125f : 1.0f;   // fold 1/sqrt(DEPTH) into Q
  int bx, by;
  xcd_remap(bx, by);
  gemm_bt_body(A, B, bb, C, MTOK, DMODEL, DMODEL, bx, by, scale);
}

// ---------------------------------------------------------------------------
// Output GEMM: 256 blocks = 1 block/CU, 2-phase double-buffer (R15: -1.5 us
// total, kept). Issue next tile's stage BEFORE compute; one barrier/iter.
// ---------------------------------------------------------------------------
__global__ __launch_bounds__(512) void gemm_out_kernel(
    const u16t* __restrict__ A, const u16t* __restrict__ W,
    const float* __restrict__ bias, float* __restrict__ C) {
  __shared__ __align__(16) u16t As[2][128 * 32];
  __shared__ __align__(16) u16t Bs[2][128 * 32];
  const int tid = threadIdx.x;
  const int wave = tid >> 6, lane = tid & 63;
  const int q = lane >> 4, t = lane & 15;
  const int srow = wave * 16 + (lane >> 2);   // staging row 0..127
  const int sch = (lane & 3) * 8;             // staging k-offset
  int bx, by;
  xcd_remap(bx, by);
  const int bm = by * 128, bn = bx * 128;
  const int wi = (wave >> 1) * 32, wj = (wave & 1) * 64;
  const int K = DMODEL, Nc = DMODEL;
  const size_t arow = (size_t)(bm + srow) * K + sch;
  const size_t brow = (size_t)(bn + srow) * K + sch;

  f32x4 acc[2][4];
#pragma unroll
  for (int i = 0; i < 2; ++i)
#pragma unroll
    for (int j = 0; j < 4; ++j) acc[i][j] = f32x4{0.f, 0.f, 0.f, 0.f};

  // prologue: stage tile kt=0 into buf 0
  load_lds16(A + arow, As[0] + wave * 512);
  load_lds16(W + brow, Bs[0] + wave * 512);
  __syncthreads();

  for (int kt = 0; kt < K; kt += 32) {
    const int cur = (kt >> 5) & 1;
    // issue next tile's stage FIRST — overlaps with this tile's compute
    if (kt + 32 < K) {
      load_lds16(A + arow + kt + 32, As[cur ^ 1] + wave * 512);
      load_lds16(W + brow + kt + 32, Bs[cur ^ 1] + wave * 512);
    }
    bf16x8 af[2], bfr[4];
#pragma unroll
    for (int i = 0; i < 2; ++i)
      af[i] = *(const bf16x8*)(As[cur] + (wi + i * 16 + t) * 32 + q * 8);
#pragma unroll
    for (int j = 0; j < 4; ++j)
      bfr[j] = *(const bf16x8*)(Bs[cur] + (wj + j * 16 + t) * 32 + q * 8);
#pragma unroll
    for (int i = 0; i < 2; ++i)
#pragma unroll
      for (int j = 0; j < 4; ++j)
        acc[i][j] = __builtin_amdgcn_mfma_f32_16x16x32_bf16(af[i], bfr[j], acc[i][j], 0, 0, 0);
    __syncthreads();   // drains this iter's prefetch; buf^1 ready for next
  }
#pragma unroll
  for (int j = 0; j < 4; ++j) {
    const int col = bn + wj + j * 16 + t;
    const float bv = bias[col];
#pragma unroll
    for (int i = 0; i < 2; ++i) {
#pragma unroll
      for (int r = 0; r < 4; ++r) {
        const int row = bm + wi + i * 16 + q * 4 + r;
        C[(size_t)row * Nc + col] = acc[i][j][r] + bv;
      }
    }
  }
}

// ---------------------------------------------------------------------------
// Fused causal attention with relative-position bias — 128-row Q-tiles.
// == R10 kernel (session best; attn warm 46-50 us, run-to-run +/-1.5 us) ==
// Binding resource: LDS instruction ISSUE, ~saturated for this structure
// (54 wave-instrs/iter/wave x 18 iters x 16 waves/CU x ~5.8cyc ~= 110k
// cycles/CU ~= measured dur). Reverted: R11 predicate-skips, R13 DPP-paired
// P-store (both added dependencies/branches that cost more than the ops).
// Structure: Es 256-slot delta-ring + Ks/Vt stride-72 + per-wave TP; bias
// skew via __shfl; 2 barriers/iter; K/V/Es reg-prefetch; T5 setprio.
// Dispatch order: i-tiles {7,6,5,4} then {0,1,2,3}. Fixed-max softmax;
// Q pre-scaled by 0.125. LDS 73.7 KB -> 2 blocks/CU.
// ---------------------------------------------------------------------------
__global__ __launch_bounds__(512, 4) void attn_kernel(
    const u16t* __restrict__ Qp, const u16t* __restrict__ Kp,
    const u16t* __restrict__ Vp, const u16t* __restrict__ Er,
    u16t* __restrict__ AO) {
  const int gx = blockIdx.x;
  const int xcd = gx & 7, slot = gx >> 3;     // group pinned to XCD
  const int ghi = slot & 7, k4 = slot >> 3;   // k4 in [0,8)
  const int T = (k4 < 4) ? (7 - k4) : (k4 - 4);   // {7,6,5,4,0,1,2,3}
  const int g = (ghi << 3) | xcd;             // 0..63 = (n,h)
  const int n = g >> 4, h = g & 15;

  const int tid = threadIdx.x;
  const int wave = tid >> 6, lane = tid & 63;
  const int q = lane >> 4, t = lane & 15;
  const int rr = tid >> 3;          // 0..63 staging row
  const int c0 = (tid & 7) * 8;     // 0..56 staging d-offset

  __shared__ __align__(16) u16t Es[256 * 72];   // 36 KB delta-ring
  __shared__ __align__(16) u16t Ks[64 * 72];    // 9 KB
  __shared__ __align__(16) u16t Vt[64 * 72];    // 9 KB [d][j^swz], stride-72
  __shared__ __align__(16) u16t TP[8 * 1152];   // 18 KB per-wave P staging
  u16t* TPw = TP + wave * 1152;

  const int I0 = T * 128;
  const int iw = I0 + wave * 16;
  const int jmax = 2 * T + 1;

  const size_t qoff = ((size_t)(n * SEQ + iw + t)) * DMODEL + h * DEPTH;
  const bf16x8 qf0 = *(const bf16x8*)(Qp + qoff + q * 8);
  const bf16x8 qf1 = *(const bf16x8*)(Qp + qoff + 32 + q * 8);

  // ---- bias shuffle pattern: src lane + lo/hi select, per target row-reg r ----
  int srcl[4];
  bool sel_lo[4];
#pragma unroll
  for (int r = 0; r < 4; ++r) {
    const int u = q * 4 + r - 1 - t;
    srcl[r] = (q << 4) | (u & 15);
    sel_lo[r] = (u >= 0);
  }

  // ---- preload Es chunks 2T, 2T+1 (delta in [128T, 128T+128)) ----
  const uint4 epre0 = *(const uint4*)(Er + ((size_t)(2 * T) * 64 + rr) * DEPTH + c0);
  const uint4 epre1 = *(const uint4*)(Er + ((size_t)(2 * T + 1) * 64 + rr) * DEPTH + c0);
  // ---- iter-0 globals ----
  const size_t kvoff0 = ((size_t)(n * SEQ + rr)) * DMODEL + h * DEPTH + c0;   // J0=0
  uint4 kv = *(const uint4*)(Kp + kvoff0);
  uint4 vv = *(const uint4*)(Vp + kvoff0);
  // chunk 2T-1 (may be OOB-below for T=0: mapped guard, garbage masked)
  uint4 ev = *(const uint4*)(Er + ((ptrdiff_t)(2 * T - 1) * 64 + rr) * DEPTH + c0);

  *(uint4*)(Es + (((2 * T) & 3) * 64 + rr) * 72 + c0) = epre0;
  *(uint4*)(Es + (((2 * T + 1) & 3) * 64 + rr) * 72 + c0) = epre1;

  f32x4 o[4];
#pragma unroll
  for (int c = 0; c < 4; ++c) o[c] = f32x4{0.f, 0.f, 0.f, 0.f};
  float l_r[4] = {0.f, 0.f, 0.f, 0.f};

  for (int jt = 0; jt <= jmax; ++jt) {
    const int J0 = jt * 64;
    const int cnew = 2 * T - 1 - jt;          // chunk staged this iter

    __syncthreads();    // previous tile fully consumed
    // ---- stage K (stride-72), Es chunk (ring, stride-72), V (transposed) ----
    *(uint4*)(Ks + rr * 72 + c0) = kv;
    *(uint4*)(Es + ((cnew & 3) * 64 + rr) * 72 + c0) = ev;
    {
      const u16t* pv = (const u16t*)&vv;
#pragma unroll
      for (int uu = 0; uu < 8; ++uu) {
        const int d = c0 + uu;
        Vt[d * 72 + (rr ^ (((d >> 2) & 7) << 3))] = pv[uu];
      }
    }
    __syncthreads();

    // ---- prefetch next-iter globals (drain overlaps compute) ----
    if (jt < jmax) {
      const size_t kvoff = ((size_t)(n * SEQ + J0 + 64 + rr)) * DMODEL + h * DEPTH + c0;
      kv = *(const uint4*)(Kp + kvoff);
      vv = *(const uint4*)(Vp + kvoff);
      ev = *(const uint4*)(Er + ((ptrdiff_t)(cnew - 1) * 64 + rr) * DEPTH + c0);
    }

    // ---- QK^T (K frags from stride-72 LDS) ----
    __builtin_amdgcn_s_setprio(1);
    f32x4 s[4];
#pragma unroll
    for (int c = 0; c < 4; ++c) s[c] = f32x4{0.f, 0.f, 0.f, 0.f};
#pragma unroll
    for (int kk = 0; kk < 2; ++kk) {
      const bf16x8 qf = kk ? qf1 : qf0;
#pragma unroll
      for (int c = 0; c < 4; ++c) {
        const bf16x8 kf = *(const bf16x8*)(Ks + (c * 16 + t) * 72 + kk * 32 + q * 8);
        s[c] = __builtin_amdgcn_mfma_f32_16x16x32_bf16(qf, kf, s[c], 0, 0, 0);
      }
    }
    // ---- bias T = Q @ Es^T over this wave's 80-wide delta window ----
    const int D0 = iw - J0 - 63;   // delta of window col 0
    f32x4 tb[5];
#pragma unroll
    for (int cc = 0; cc < 5; ++cc) tb[cc] = f32x4{0.f, 0.f, 0.f, 0.f};
#pragma unroll
    for (int kk = 0; kk < 2; ++kk) {
      const bf16x8 qf = kk ? qf1 : qf0;
#pragma unroll
      for (int cc = 0; cc < 5; ++cc) {
        const int sl = (int)(((unsigned)(D0 + cc * 16 + t)) & 255u);
        const bf16x8 ef = *(const bf16x8*)(Es + sl * 72 + kk * 32 + q * 8);
        tb[cc] = __builtin_amdgcn_mfma_f32_16x16x32_bf16(qf, ef, tb[cc], 0, 0, 0);
      }
    }
    __builtin_amdgcn_s_setprio(0);

    // ---- skew transfer in-register: sh[cc][r] = tb[cc][r] from srcl[r] ----
    float sh[5][4];
#pragma unroll
    for (int cc = 0; cc < 5; ++cc)
#pragma unroll
      for (int r = 0; r < 4; ++r)
        sh[cc][r] = __shfl(tb[cc][r], srcl[r], 64);

    // ---- logits + causal mask + fixed-max softmax numerator ----
    const int dIJ = I0 - J0;
#pragma unroll
    for (int c = 0; c < 4; ++c) {
      const int jc = c * 16 + t;               // j - J0
#pragma unroll
      for (int r = 0; r < 4; ++r) {
        const int ic = wave * 16 + q * 4 + r;  // i - I0
        const float bias = sel_lo[r] ? sh[4 - c][r] : sh[3 - c][r];
        float lg = s[c][r] + bias;
        lg = (jc <= ic + dIJ) ? lg : -1e30f;
        const float pr = __expf(lg);
        s[c][r] = pr;
        l_r[r] += pr;
      }
    }
    // ---- P -> LDS in A-operand layout (same-wave order) ----
#pragma unroll
    for (int c = 0; c < 4; ++c)
#pragma unroll
      for (int r = 0; r < 4; ++r)
        TPw[(q * 4 + r) * 72 + c * 16 + t] = f2bf(s[c][r]);

    const bf16x8 pf0 = *(const bf16x8*)(TPw + t * 72 + q * 8);
    const bf16x8 pf1 = *(const bf16x8*)(TPw + t * 72 + 32 + q * 8);
    __builtin_amdgcn_s_setprio(1);
#pragma unroll
    for (int c2 = 0; c2 < 4; ++c2) {
      const int dd = c2 * 16 + t;
      const int sw = (dd >> 2) & 7;
      const bf16x8 v0 = *(const bf16x8*)(Vt + dd * 72 + ((0 + q) ^ sw) * 8);
      const bf16x8 v1 = *(const bf16x8*)(Vt + dd * 72 + ((4 + q) ^ sw) * 8);
      o[c2] = __builtin_amdgcn_mfma_f32_16x16x32_bf16(pf0, v0, o[c2], 0, 0, 0);
      o[c2] = __builtin_amdgcn_mfma_f32_16x16x32_bf16(pf1, v1, o[c2], 0, 0, 0);
    }
    __builtin_amdgcn_s_setprio(0);
  }

  // ---- epilogue: reduce l over the 16 t-lanes, normalize, store ----
#pragma unroll
  for (int r = 0; r < 4; ++r) {
    float lsum = l_r[r];
    lsum += __shfl_xor(lsum, 1, 64);
    lsum += __shfl_xor(lsum, 2, 64);
    lsum += __shfl_xor(lsum, 4, 64);
    lsum += __shfl_xor(lsum, 8, 64);
    const float inv = 1.f / lsum;
    const size_t obase = ((size_t)(n * SEQ + iw + q * 4 + r)) * DMODEL + h * DEPTH;
#pragma unroll
    for (int c2 = 0; c2 < 4; ++c2)
      AO[obase + c2 * 16 + t] = f2bf(o[c2][r] * inv);
  }
}

// ---------------------------------------------------------------------------
extern "C" void kernel_launch(void* const* d_in, const int* in_sizes, int n_in,
                              void* d_out, int out_size, void* d_ws, size_t ws_size,
                              hipStream_t stream) {
  const float* q_in = (const float*)d_in[0];
  const float* k_in = (const float*)d_in[1];
  const float* v_in = (const float*)d_in[2];
  // d_in[3] = mask (causal; analytic)
  const float* Wq = (const float*)d_in[4];
  const float* bq = (const float*)d_in[5];
  const float* Wk = (const float*)d_in[6];
  const float* bk = (const float*)d_in[7];
  const float* Wv = (const float*)d_in[8];
  const float* bv = (const float*)d_in[9];
  const float* Wo = (const float*)d_in[10];
  const float* bo = (const float*)d_in[11];
  const float* pe = (const float*)d_in[12];
  float* out = (float*)d_out;

  char* ws = (char*)d_ws;
  constexpr size_t MB = 1ull << 20;
  u16t* qb  = (u16t*)(ws);            // 8 MB [prep..qkv]
  u16t* kb  = (u16t*)(ws + 8 * MB);
  u16t* vb  = (u16t*)(ws + 16 * MB);
  u16t* Qp  = (u16t*)(ws + 24 * MB);
  u16t* Kp  = (u16t*)(ws + 32 * MB);
  u16t* Vp  = (u16t*)(ws + 40 * MB);
  u16t* AOb = (u16t*)(ws + 48 * MB);
  u16t* WqT = (u16t*)(ws + 56 * MB);
  u16t* WkT = (u16t*)(ws + 58 * MB);
  u16t* WvT = (u16t*)(ws + 60 * MB);
  u16t* WoT = (u16t*)(ws + 62 * MB);
  // Erel at +64MB+16KB: 16 KB mapped guard below (ring chunk reads reach
  // down to Erl-16KB for fully-masked windows), 128 KB table above.
  u16t* Erl = (u16t*)(ws + 64 * MB + 16 * 1024);

  const size_t SZA = (size_t)MTOK * DMODEL;
  const int n8 = (int)(SZA / 8);
  // z<3: cvt planes (blocks past n8/256 exit); z==3: 5120 transpose blocks.
  prep_kernel<<<dim3(5120, 1, 4), 256, 0, stream>>>(
      q_in, k_in, v_in, qb, kb, vb, n8,
      Wq, Wk, Wv, Wo, WqT, WkT, WvT, WoT, pe, Erl);

  gemm_qkv_kernel<<<dim3(DMODEL / 128, MTOK / 128, 3), 256, 0, stream>>>(
      qb, kb, vb, WqT, WkT, WvT, bq, bk, bv, Qp, Kp, Vp);

  attn_kernel<<<dim3(512, 1, 1), 512, 0, stream>>>(Qp, Kp, Vp, Erl, AOb);

  gemm_out_kernel<<<dim3(DMODEL / 128, MTOK / 128, 1), 512, 0, stream>>>(AOb, WoT, bo, out);
}